// Round 13
// baseline (252.430 us; speedup 1.0000x reference)
//
#include <hip/hip_runtime.h>
#include <hip/hip_bf16.h>
#include <math.h>

typedef __bf16 bf16;
typedef __bf16 bf16x8 __attribute__((ext_vector_type(8)));
typedef __bf16 bf16x4v __attribute__((ext_vector_type(4)));
typedef float f32x4 __attribute__((ext_vector_type(4)));
typedef float f32x16 __attribute__((ext_vector_type(16)));
typedef unsigned int u32x2 __attribute__((ext_vector_type(2)));
typedef unsigned int u32x4 __attribute__((ext_vector_type(4)));

#define MFMA16(a, b, c) __builtin_amdgcn_mfma_f32_16x16x32_bf16((a), (b), (c), 0, 0, 0)
#define MFMA32(a, b, c) __builtin_amdgcn_mfma_f32_32x32x16_bf16((a), (b), (c), 0, 0, 0)

static constexpr int Bsz = 2, Tsz = 2048, Csz = 2048, Hn = 16, Dh = 128;
static constexpr float ATTN_SCALE = 0.08838834764831845f; // 1/sqrt(128)

__device__ __forceinline__ void gld16(const void* src, void* dst) {
    __builtin_amdgcn_global_load_lds((__attribute__((address_space(1))) void*)src,
                                     (__attribute__((address_space(3))) void*)dst,
                                     16, 0, 0);
}

__device__ __forceinline__ unsigned cvt_pk_bf16(float lo, float hi) {
    unsigned r;
    asm("v_cvt_pk_bf16_f32 %0, %1, %2" : "=v"(r) : "v"(lo), "v"(hi));
    return r;
}

__device__ __forceinline__ bf16x8 make_pfrag(float p0, float p1, float p2, float p3,
                                             float p4, float p5, float p6, float p7) {
    unsigned a0 = cvt_pk_bf16(p0, p1), a1 = cvt_pk_bf16(p2, p3);
    unsigned b0 = cvt_pk_bf16(p4, p5), b1 = cvt_pk_bf16(p6, p7);
    asm volatile("v_permlane32_swap_b32 %0, %1" : "+v"(a0), "+v"(b0));
    asm volatile("v_permlane32_swap_b32 %0, %1" : "+v"(a1), "+v"(b1));
    u32x4 w = {a0, a1, b0, b1};
    return __builtin_bit_cast(bf16x8, w);
}

// ---------------- cast x (f32 -> bf16), 8 elems/thread ----------------
__global__ __launch_bounds__(256) void cast_x_kernel(const float* __restrict__ x,
                                                     bf16* __restrict__ o, int n8) {
    int i = blockIdx.x * 256 + threadIdx.x;
    if (i >= n8) return;
    const float4* x4 = (const float4*)x;
    float4 a = x4[2 * i], b = x4[2 * i + 1];
    bf16x8 v;
    v[0] = (bf16)a.x; v[1] = (bf16)a.y; v[2] = (bf16)a.z; v[3] = (bf16)a.w;
    v[4] = (bf16)b.x; v[5] = (bf16)b.y; v[6] = (bf16)b.z; v[7] = (bf16)b.w;
    ((bf16x8*)o)[i] = v;
}

// ---------------- tiled transpose-cast: out[c][r] = in[r][c], bf16x4 writes ----------------
template <typename TIN>
__global__ __launch_bounds__(256) void transpose_cast_kernel(const TIN* __restrict__ in,
                                                             bf16* __restrict__ out,
                                                             int R, int Cc) {
    __shared__ float tile[64][65];
    const int tx = threadIdx.x, ty = threadIdx.y;
    in  += (size_t)blockIdx.z * R * Cc;
    out += (size_t)blockIdx.z * R * Cc;
    const int c0 = blockIdx.x * 64, r0 = blockIdx.y * 64;
#pragma unroll
    for (int j = 0; j < 16; ++j) {
        int rr = ty + j * 4;
        tile[rr][tx] = (float)in[(size_t)(r0 + rr) * Cc + c0 + tx];
    }
    __syncthreads();
    const int q = (tx & 15) << 2;  // row-quad base
    const int cg = tx >> 4;        // col-group [0,4)
#pragma unroll
    for (int j = 0; j < 4; ++j) {
        const int cc = j * 16 + cg * 4 + ty;
        bf16x4v v;
        v[0] = (bf16)tile[q + 0][cc];
        v[1] = (bf16)tile[q + 1][cc];
        v[2] = (bf16)tile[q + 2][cc];
        v[3] = (bf16)tile[q + 3][cc];
        *(bf16x4v*)(out + (size_t)(c0 + cc) * R + r0 + q) = v;
    }
}

// ---------------- rope cos/sin table ----------------
__global__ __launch_bounds__(256) void cossin_kernel(float2* __restrict__ cs) {
    int idx = blockIdx.x * 256 + threadIdx.x; // 2048*64
    int t = idx >> 6, i = idx & 63;
    float theta = 1.0f / powf(10000.0f, (float)(2 * i) / 128.0f);
    float ang = (float)t * theta;
    cs[idx] = make_float2(cosf(ang), sinf(ang));
}

// =============== 128x384 GEMM, deep counted-vmcnt pipeline (round-5/8 best) ===============
// Fused epilogue: rope+head-split for Q/K; V written DIRECTLY as V^T [B,H,D,T].
__global__ __launch_bounds__(512, 2)
void gemm384_qkv(const bf16* __restrict__ A, const bf16* __restrict__ Bt,
                 bf16* __restrict__ Oq, bf16* __restrict__ Ok, bf16* __restrict__ Vt,
                 const float2* __restrict__ cs, int K) {
    __shared__ bf16 sA[2][128 * 64];
    __shared__ bf16 sB[2][384 * 64];
    const int tid = threadIdx.x, lane = tid & 63, wid = tid >> 6;
    const int wm = wid >> 2, wn = wid & 3;
    const int lo16 = lane & 15, hi4 = lane >> 4;

    const int cpx = gridDim.x >> 3;
    const int swz = (blockIdx.x & 7) * cpx + (blockIdx.x >> 3);
    const int by = swz & 31;   // M/128 = 32
    const int bx = swz >> 5;   // N/384 = 16
    const int row0 = by << 7, col0 = bx * 384;

    const int srow = tid >> 3;                                   // [0,64)
    const int swzoff = (((tid & 7) ^ ((tid >> 3) & 7)) << 3);    // elements
    const bf16* srcA = A  + (size_t)(row0 + srow) * K + swzoff;
    const bf16* srcB = Bt + (size_t)(col0 + srow) * K + swzoff;
    const size_t K64 = (size_t)K * 64;
    char* const ldsA = (char*)&sA[0][0];
    char* const ldsB = (char*)&sB[0][0];
    const int wuo = wid << 10;

    auto issueA = [&](int c, int kt) {   // A tile 128x64 = 16KB
        const bf16* s = srcA + (size_t)kt * 64;
        gld16(s,       ldsA + c * 16384 + 0    + wuo);
        gld16(s + K64, ldsA + c * 16384 + 8192 + wuo);
    };
    auto issueB = [&](int c, int kt, int u) { // B rows [128u, 128u+128) = 16KB
        const bf16* s = srcB + (size_t)kt * 64 + (size_t)(2 * u) * K64;
        gld16(s,       ldsB + c * 49152 + u * 16384 + 0    + wuo);
        gld16(s + K64, ldsB + c * 49152 + u * 16384 + 8192 + wuo);
    };
    auto ldF = [&](const char* buf, int row, int ks) {
        return *(const bf16x8*)(buf + row * 128 + ((((ks << 2) + hi4) ^ (row & 7)) << 4));
    };

    const int arow = (wm << 6) + lo16;   // + mi*16, mi in [0,4)
    const int brow = (wn << 4) + lo16;   // + nj*64, nj in [0,6)

    f32x4 acc[4][6] = {};
    const int nkt = K >> 6;

    issueA(0, 0); issueB(0, 0, 0); issueB(0, 0, 1); issueB(0, 0, 2);
    asm volatile("s_waitcnt vmcnt(4)" ::: "memory");
    __builtin_amdgcn_s_barrier();

    for (int kt = 0; kt < nkt - 1; ++kt) {
        const int c = kt & 1;
        const char* bufA = ldsA + c * 16384;
        const char* bufB = ldsB + c * 49152;
        bf16x8 af[4][2], bq[2][2];
        // ---- phase 0: nj {0,1} ----
#pragma unroll
        for (int i = 0; i < 4; ++i) {
            af[i][0] = ldF(bufA, arow + (i << 4), 0);
            af[i][1] = ldF(bufA, arow + (i << 4), 1);
        }
#pragma unroll
        for (int j = 0; j < 2; ++j) {
            bq[j][0] = ldF(bufB, brow + (j << 6), 0);
            bq[j][1] = ldF(bufB, brow + (j << 6), 1);
        }
        issueA(c ^ 1, kt + 1); issueB(c ^ 1, kt + 1, 0); issueB(c ^ 1, kt + 1, 1);
        __builtin_amdgcn_s_barrier();
        asm volatile("s_waitcnt lgkmcnt(0)" ::: "memory");
        __builtin_amdgcn_sched_barrier(0);
        __builtin_amdgcn_s_setprio(1);
#pragma unroll
        for (int ks = 0; ks < 2; ++ks)
#pragma unroll
            for (int i = 0; i < 4; ++i)
#pragma unroll
                for (int j = 0; j < 2; ++j)
                    acc[i][j] = MFMA16(af[i][ks], bq[j][ks], acc[i][j]);
        __builtin_amdgcn_s_setprio(0);
        asm volatile("s_waitcnt vmcnt(8)" ::: "memory"); // B-b(kt) landed
        __builtin_amdgcn_s_barrier();
        // ---- phase 1: nj {2,3} ----
#pragma unroll
        for (int j = 0; j < 2; ++j) {
            bq[j][0] = ldF(bufB, brow + ((j + 2) << 6), 0);
            bq[j][1] = ldF(bufB, brow + ((j + 2) << 6), 1);
        }
        issueB(c ^ 1, kt + 1, 2);
        __builtin_amdgcn_s_barrier();
        asm volatile("s_waitcnt lgkmcnt(0)" ::: "memory");
        __builtin_amdgcn_sched_barrier(0);
        __builtin_amdgcn_s_setprio(1);
#pragma unroll
        for (int ks = 0; ks < 2; ++ks)
#pragma unroll
            for (int i = 0; i < 4; ++i)
#pragma unroll
                for (int j = 0; j < 2; ++j)
                    acc[i][j + 2] = MFMA16(af[i][ks], bq[j][ks], acc[i][j + 2]);
        __builtin_amdgcn_s_setprio(0);
        asm volatile("s_waitcnt vmcnt(8)" ::: "memory"); // B-c(kt) landed
        __builtin_amdgcn_s_barrier();
        // ---- phase 2: nj {4,5} ----
#pragma unroll
        for (int j = 0; j < 2; ++j) {
            bq[j][0] = ldF(bufB, brow + ((j + 4) << 6), 0);
            bq[j][1] = ldF(bufB, brow + ((j + 4) << 6), 1);
        }
        __builtin_amdgcn_s_barrier();
        asm volatile("s_waitcnt lgkmcnt(0)" ::: "memory");
        __builtin_amdgcn_sched_barrier(0);
        __builtin_amdgcn_s_setprio(1);
#pragma unroll
        for (int ks = 0; ks < 2; ++ks)
#pragma unroll
            for (int i = 0; i < 4; ++i)
#pragma unroll
                for (int j = 0; j < 2; ++j)
                    acc[i][j + 4] = MFMA16(af[i][ks], bq[j][ks], acc[i][j + 4]);
        __builtin_amdgcn_s_setprio(0);
        asm volatile("s_waitcnt vmcnt(4)" ::: "memory"); // A(kt+1), B-a(kt+1) landed
        __builtin_amdgcn_s_barrier();
    }

    { // ---- peeled last tile ----
        const int c = (nkt - 1) & 1;
        const char* bufA = ldsA + c * 16384;
        const char* bufB = ldsB + c * 49152;
        bf16x8 af[4][2], bq[2][2];
#pragma unroll
        for (int i = 0; i < 4; ++i) {
            af[i][0] = ldF(bufA, arow + (i << 4), 0);
            af[i][1] = ldF(bufA, arow + (i << 4), 1);
        }
#pragma unroll
        for (int j = 0; j < 2; ++j) {
            bq[j][0] = ldF(bufB, brow + (j << 6), 0);
            bq[j][1] = ldF(bufB, brow + (j << 6), 1);
        }
        __builtin_amdgcn_s_barrier();
        asm volatile("s_waitcnt lgkmcnt(0)" ::: "memory");
        __builtin_amdgcn_sched_barrier(0);
        __builtin_amdgcn_s_setprio(1);
#pragma unroll
        for (int ks = 0; ks < 2; ++ks)
#pragma unroll
            for (int i = 0; i < 4; ++i)
#pragma unroll
                for (int j = 0; j < 2; ++j)
                    acc[i][j] = MFMA16(af[i][ks], bq[j][ks], acc[i][j]);
        __builtin_amdgcn_s_setprio(0);
        asm volatile("s_waitcnt vmcnt(2)" ::: "memory");
        __builtin_amdgcn_s_barrier();
#pragma unroll
        for (int j = 0; j < 2; ++j) {
            bq[j][0] = ldF(bufB, brow + ((j + 2) << 6), 0);
            bq[j][1] = ldF(bufB, brow + ((j + 2) << 6), 1);
        }
        __builtin_amdgcn_s_barrier();
        asm volatile("s_waitcnt lgkmcnt(0)" ::: "memory");
        __builtin_amdgcn_sched_barrier(0);
        __builtin_amdgcn_s_setprio(1);
#pragma unroll
        for (int ks = 0; ks < 2; ++ks)
#pragma unroll
            for (int i = 0; i < 4; ++i)
#pragma unroll
                for (int j = 0; j < 2; ++j)
                    acc[i][j + 2] = MFMA16(af[i][ks], bq[j][ks], acc[i][j + 2]);
        __builtin_amdgcn_s_setprio(0);
        asm volatile("s_waitcnt vmcnt(0)" ::: "memory");
        __builtin_amdgcn_s_barrier();
#pragma unroll
        for (int j = 0; j < 2; ++j) {
            bq[j][0] = ldF(bufB, brow + ((j + 4) << 6), 0);
            bq[j][1] = ldF(bufB, brow + ((j + 4) << 6), 1);
        }
        __builtin_amdgcn_s_barrier();
        asm volatile("s_waitcnt lgkmcnt(0)" ::: "memory");
        __builtin_amdgcn_sched_barrier(0);
        __builtin_amdgcn_s_setprio(1);
#pragma unroll
        for (int ks = 0; ks < 2; ++ks)
#pragma unroll
            for (int i = 0; i < 4; ++i)
#pragma unroll
                for (int j = 0; j < 2; ++j)
                    acc[i][j + 4] = MFMA16(af[i][ks], bq[j][ks], acc[i][j + 4]);
        __builtin_amdgcn_s_setprio(0);
    }

    // ---- epilogue: rope + head split (Q/K); direct V^T write (V) ----
    const int d = (wn << 4) + lo16; // [0,64)
#pragma unroll
    for (int p = 0; p < 3; ++p) {
        const int gcb = col0 + (p << 7);
        const int seg = gcb >> 11;            // 0=q 1=k 2=v
        const int hb = (gcb >> 7) & 15;
        if (seg < 2) {
            bf16* dst0 = (seg == 0) ? Oq : Ok;
            const float qs = (seg == 0) ? ATTN_SCALE : 1.0f;
#pragma unroll
            for (int mi = 0; mi < 4; ++mi)
#pragma unroll
                for (int r = 0; r < 4; ++r) {
                    const int gm = row0 + (wm << 6) + (mi << 4) + (hi4 << 2) + r;
                    const int b = gm >> 11, t = gm & 2047;
                    const float2 csv = cs[t * 64 + d];
                    bf16* drow = dst0 + ((((size_t)b * Hn + hb) * Tsz + t) << 7);
                    const float vlo = acc[mi][2 * p][r];
                    const float vhi = acc[mi][2 * p + 1][r];
                    drow[d]      = (bf16)((vlo * csv.x - vhi * csv.y) * qs);
                    drow[d + 64] = (bf16)((vhi * csv.x + vlo * csv.y) * qs);
                }
        } else {
            // V^T [B,H,D,T]: r=0..3 are consecutive t -> one u32x2 (4 bf16) per d
#pragma unroll
            for (int mi = 0; mi < 4; ++mi) {
                const int t0 = row0 + (wm << 6) + (mi << 4) + (hi4 << 2);
                const int b = t0 >> 11, tt = t0 & 2047;
                bf16* vbase = Vt + (((size_t)b * Hn + hb) * Dh) * Tsz + tt;
                u32x2 wlo = {cvt_pk_bf16(acc[mi][2 * p][0], acc[mi][2 * p][1]),
                             cvt_pk_bf16(acc[mi][2 * p][2], acc[mi][2 * p][3])};
                u32x2 whi = {cvt_pk_bf16(acc[mi][2 * p + 1][0], acc[mi][2 * p + 1][1]),
                             cvt_pk_bf16(acc[mi][2 * p + 1][2], acc[mi][2 * p + 1][3])};
                *(u32x2*)(vbase + (size_t)d * Tsz)        = wlo;
                *(u32x2*)(vbase + (size_t)(d + 64) * Tsz) = whi;
            }
        }
    }
}

// =============== 128x256 output-projection GEMM, counted 2-phase (round-8) ===============
__global__ __launch_bounds__(512, 2)
void gemm256_proj(const bf16* __restrict__ A, const bf16* __restrict__ Bt,
                  float* __restrict__ Cf, int K) {
    __shared__ bf16 sA[2][128 * 64];
    __shared__ bf16 sB[2][256 * 64];
    const int tid = threadIdx.x, lane = tid & 63, wid = tid >> 6;
    const int wm = wid >> 2, wn = wid & 3;
    const int lo16 = lane & 15, hi4 = lane >> 4;
    const int N = 2048;

    const int cpx = gridDim.x >> 3;
    const int swz = (blockIdx.x & 7) * cpx + (blockIdx.x >> 3);
    const int by = swz & 31;   // M/128 = 32
    const int bx = swz >> 5;   // N/256 = 8
    const int row0 = by << 7, col0 = bx << 8;

    const int srow = tid >> 3;
    const int swzoff = (((tid & 7) ^ ((tid >> 3) & 7)) << 3);
    const bf16* srcA = A  + (size_t)(row0 + srow) * K + swzoff;
    const bf16* srcB = Bt + (size_t)(col0 + srow) * K + swzoff;
    const size_t K64 = (size_t)K * 64;
    char* const ldsA = (char*)&sA[0][0];
    char* const ldsB = (char*)&sB[0][0];
    const int wuo = wid << 10;

    auto issueA = [&](int c, int kt) {
        const bf16* s = srcA + (size_t)kt * 64;
        gld16(s,       ldsA + c * 16384 + 0    + wuo);
        gld16(s + K64, ldsA + c * 16384 + 8192 + wuo);
    };
    auto issueB = [&](int c, int kt, int u) { // B rows [128u, 128u+128)
        const bf16* s = srcB + (size_t)kt * 64 + (size_t)(2 * u) * K64;
        gld16(s,       ldsB + c * 32768 + u * 16384 + 0    + wuo);
        gld16(s + K64, ldsB + c * 32768 + u * 16384 + 8192 + wuo);
    };
    auto ldF = [&](const char* buf, int row, int ks) {
        return *(const bf16x8*)(buf + row * 128 + ((((ks << 2) + hi4) ^ (row & 7)) << 4));
    };

    const int arow = (wm << 6) + lo16;   // + mi*16
    const int brow = (wn << 4) + lo16;   // + nj*64, nj in [0,4)

    f32x4 acc[4][4] = {};
    const int nkt = K >> 6;

    issueA(0, 0); issueB(0, 0, 0); issueB(0, 0, 1);
    if (nkt > 1) { issueA(1, 1); issueB(1, 1, 0); }
    asm volatile("s_waitcnt vmcnt(4)" ::: "memory");
    __builtin_amdgcn_s_barrier();

    for (int kt = 0; kt < nkt; ++kt) {
        const int c = kt & 1;
        const char* bufA = ldsA + c * 16384;
        const char* bufB = ldsB + c * 32768;
        bf16x8 af[4][2], bq[2][2];
        // ---- phase 0: nj {0,1} (+ all A frags) ----
#pragma unroll
        for (int i = 0; i < 4; ++i) {
            af[i][0] = ldF(bufA, arow + (i << 4), 0);
            af[i][1] = ldF(bufA, arow + (i << 4), 1);
        }
#pragma unroll
        for (int j = 0; j < 2; ++j) {
            bq[j][0] = ldF(bufB, brow + (j << 6), 0);
            bq[j][1] = ldF(bufB, brow + (j << 6), 1);
        }
        if (kt + 1 < nkt) issueB(c ^ 1, kt + 1, 1);   // Bb(kt+1)
        __builtin_amdgcn_s_barrier();
        asm volatile("s_waitcnt lgkmcnt(0)" ::: "memory");
        __builtin_amdgcn_sched_barrier(0);
        __builtin_amdgcn_s_setprio(1);
#pragma unroll
        for (int ks = 0; ks < 2; ++ks)
#pragma unroll
            for (int i = 0; i < 4; ++i)
#pragma unroll
                for (int j = 0; j < 2; ++j)
                    acc[i][j] = MFMA16(af[i][ks], bq[j][ks], acc[i][j]);
        __builtin_amdgcn_s_setprio(0);
        if (kt + 1 < nkt) asm volatile("s_waitcnt vmcnt(6)" ::: "memory");
        else              asm volatile("s_waitcnt vmcnt(0)" ::: "memory");
        __builtin_amdgcn_s_barrier();
        // ---- phase 1: nj {2,3} ----
#pragma unroll
        for (int j = 0; j < 2; ++j) {
            bq[j][0] = ldF(bufB, brow + ((j + 2) << 6), 0);
            bq[j][1] = ldF(bufB, brow + ((j + 2) << 6), 1);
        }
        if (kt + 2 < nkt) { issueA(c, kt + 2); issueB(c, kt + 2, 0); }
        __builtin_amdgcn_s_barrier();
        asm volatile("s_waitcnt lgkmcnt(0)" ::: "memory");
        __builtin_amdgcn_sched_barrier(0);
        __builtin_amdgcn_s_setprio(1);
#pragma unroll
        for (int ks = 0; ks < 2; ++ks)
#pragma unroll
            for (int i = 0; i < 4; ++i)
#pragma unroll
                for (int j = 0; j < 2; ++j)
                    acc[i][j + 2] = MFMA16(af[i][ks], bq[j][ks], acc[i][j + 2]);
        __builtin_amdgcn_s_setprio(0);
        if (kt + 2 < nkt)      asm volatile("s_waitcnt vmcnt(6)" ::: "memory");
        else if (kt + 1 < nkt) asm volatile("s_waitcnt vmcnt(2)" ::: "memory");
        __builtin_amdgcn_s_barrier();
    }

    // ---- epilogue: plain f32 C write ----
#pragma unroll
    for (int mi = 0; mi < 4; ++mi)
#pragma unroll
        for (int r = 0; r < 4; ++r) {
            const int gm = row0 + (wm << 6) + (mi << 4) + (hi4 << 2) + r;
            float* crow = Cf + (size_t)gm * N + col0 + (wn << 4) + lo16;
#pragma unroll
            for (int nj = 0; nj < 4; ++nj)
                crow[nj << 6] = acc[mi][nj][r];
        }
}

// ---------------- flash attention: paired q-tiles, XCD-pinned KV ----------------
// Grid 256: xcd = i&7 owns bh {4*xcd..4*xcd+3}; slot>>2 = pair p; block handles
// q-tiles (15-p, p) of ONE bh over a single kv sweep (KV staged once; uniform
// 34 compute-units/block). KV/bh = 1 MB; 4 bh/XCD = 4 MB L2-resident.
__device__ __forceinline__ void stage_tile(const bf16* __restrict__ Kb,
                                           const bf16* __restrict__ Vtb,
                                           bf16* sKc, bf16* sVc, int k0, int tid) {
#pragma unroll
    for (int c = 0; c < 4; ++c) {
        const int off = (c << 12) + (tid << 4);
        const int row = off >> 8, u = (off >> 4) & 15;
        gld16(Kb + (size_t)(k0 + row) * Dh + ((u ^ (row & 7)) << 3), (char*)sKc + off);
        const int dv = off >> 7, uv = (off >> 4) & 7;
        gld16(Vtb + (size_t)dv * Tsz + k0 + ((uv ^ (dv & 7)) << 3), (char*)sVc + off);
    }
}

__device__ __forceinline__ void attn_tile(const bf16* kbuf, const bf16* vbuf,
                                          const bf16x8* qf, int k0, int q0w, int qg,
                                          int lo32, int hl,
                                          float& m, float& lsum, f32x16* o) {
    f32x16 s0 = {}, s1 = {};
    const int swk = lo32 & 7;
    __builtin_amdgcn_s_setprio(1);
#pragma unroll
    for (int kc = 0; kc < 8; ++kc) {
        bf16x8 kf0 = *(const bf16x8*)((const char*)kbuf + lo32 * 256 +
                      ((((kc << 1) + hl) ^ swk) << 4));
        s0 = MFMA32(kf0, qf[kc], s0);
        bf16x8 kf1 = *(const bf16x8*)((const char*)kbuf + (32 + lo32) * 256 +
                      ((((kc << 1) + hl) ^ swk) << 4));
        s1 = MFMA32(kf1, qf[kc], s1);
    }
    __builtin_amdgcn_s_setprio(0);

    const bool bnd = (k0 + 63 > q0w);
    if (bnd) {
#pragma unroll
        for (int r = 0; r < 16; ++r) {
            const int kl = (r & 3) + ((r >> 2) << 3) + (hl << 2);
            if (k0 + kl > qg)      s0[r] = -1e30f;
            if (k0 + 32 + kl > qg) s1[r] = -1e30f;
        }
    }
    float pm = s0[0];
#pragma unroll
    for (int r = 1; r < 16; ++r) pm = fmaxf(pm, s0[r]);
#pragma unroll
    for (int r = 0; r < 16; ++r) pm = fmaxf(pm, s1[r]);
    pm = fmaxf(pm, __shfl_xor(pm, 32));

    if (__any(pm > m + 8.0f)) {
        const float mn = fmaxf(m, pm);
        const float sc = __expf(m - mn);
        m = mn;
        lsum *= sc;
#pragma unroll
        for (int db = 0; db < 4; ++db)
#pragma unroll
            for (int r = 0; r < 16; ++r) o[db][r] *= sc;
    }
    float rs = 0.f;
    if (bnd) {
#pragma unroll
        for (int r = 0; r < 16; ++r) {
            float e0 = (s0[r] > -1e29f) ? __expf(s0[r] - m) : 0.f;
            float e1 = (s1[r] > -1e29f) ? __expf(s1[r] - m) : 0.f;
            s0[r] = e0; s1[r] = e1; rs += e0 + e1;
        }
    } else {
#pragma unroll
        for (int r = 0; r < 16; ++r) {
            float e0 = __expf(s0[r] - m);
            float e1 = __expf(s1[r] - m);
            s0[r] = e0; s1[r] = e1; rs += e0 + e1;
        }
    }
    rs += __shfl_xor(rs, 32);
    lsum += rs;

    bf16x8 pb0 = make_pfrag(s0[0], s0[1], s0[2],  s0[3],  s0[4],  s0[5],  s0[6],  s0[7]);
    bf16x8 pb1 = make_pfrag(s0[8], s0[9], s0[10], s0[11], s0[12], s0[13], s0[14], s0[15]);
    bf16x8 pb2 = make_pfrag(s1[0], s1[1], s1[2],  s1[3],  s1[4],  s1[5],  s1[6],  s1[7]);
    bf16x8 pb3 = make_pfrag(s1[8], s1[9], s1[10], s1[11], s1[12], s1[13], s1[14], s1[15]);

    __builtin_amdgcn_s_setprio(1);
#pragma unroll
    for (int db = 0; db < 4; ++db) {
        const int rd = (db << 5) + lo32;
        const char* vrow = (const char*)vbuf + rd * 128;
        const int sw = rd & 7;
        bf16x8 v0 = *(const bf16x8*)(vrow + (((0 + hl) ^ sw) << 4));
        o[db] = MFMA32(v0, pb0, o[db]);
        bf16x8 v1 = *(const bf16x8*)(vrow + (((2 + hl) ^ sw) << 4));
        o[db] = MFMA32(v1, pb1, o[db]);
        bf16x8 v2 = *(const bf16x8*)(vrow + (((4 + hl) ^ sw) << 4));
        o[db] = MFMA32(v2, pb2, o[db]);
        bf16x8 v3 = *(const bf16x8*)(vrow + (((6 + hl) ^ sw) << 4));
        o[db] = MFMA32(v3, pb3, o[db]);
    }
    __builtin_amdgcn_s_setprio(0);
}

__global__ __launch_bounds__(256, 1)
void attn_kernel(const bf16* __restrict__ Q, const bf16* __restrict__ K,
                 const bf16* __restrict__ Vt, bf16* __restrict__ Y) {
    __shared__ bf16 sK[2][64 * 128];
    __shared__ bf16 sV[2][128 * 64];
    const int tid = threadIdx.x, lane = tid & 63, wv = tid >> 6;
    const int lo32 = lane & 31, hl = lane >> 5;

    const int i = blockIdx.x;
    const int slot = i >> 3;
    const int bh = ((i & 7) << 2) + (slot & 3);  // XCD-pinned bh
    const int p = slot >> 2;                      // pair index 0..7
    const int t_hi = 15 - p, t_lo = p;
    const int b = bh >> 4, h = bh & 15;

    const bf16* Kb  = K  + (size_t)bh * (Tsz * Dh);
    const bf16* Vtb = Vt + (size_t)bh * (Tsz * Dh);
    const bf16* Qbh = Q  + (size_t)bh * (Tsz * Dh);

    const int q0w_hi = (t_hi << 7) + (wv << 5), qg_hi = q0w_hi + lo32;
    const int q0w_lo = (t_lo << 7) + (wv << 5), qg_lo = q0w_lo + lo32;

    bf16x8 qfh[8], qfl[8];
#pragma unroll
    for (int kc = 0; kc < 8; ++kc) {
        qfh[kc] = *(const bf16x8*)(Qbh + (size_t)qg_hi * Dh + (kc << 4) + (hl << 3));
        qfl[kc] = *(const bf16x8*)(Qbh + (size_t)qg_lo * Dh + (kc << 4) + (hl << 3));
    }

    float mh = -1e30f, lh = 0.f, ml = -1e30f, ll = 0.f;
    f32x16 oh[4] = {}, ol[4] = {};

    const int nt = 2 * t_hi + 2;
    const int nth = ((q0w_hi + 31) >> 6) + 1;
    const int ntl = ((q0w_lo + 31) >> 6) + 1;

    stage_tile(Kb, Vtb, &sK[0][0], &sV[0][0], 0, tid);

    int cur = 0;
    for (int kt = 0; kt < nt; ++kt) {
        __syncthreads();
        if (kt + 1 < nt)
            stage_tile(Kb, Vtb, &sK[cur ^ 1][0], &sV[cur ^ 1][0], (kt + 1) << 6, tid);
        const bf16* kbuf = &sK[cur][0];
        const bf16* vbuf = &sV[cur][0];
        const int k0 = kt << 6;
        if (kt < nth) attn_tile(kbuf, vbuf, qfh, k0, q0w_hi, qg_hi, lo32, hl, mh, lh, oh);
        if (kt < ntl) attn_tile(kbuf, vbuf, qfl, k0, q0w_lo, qg_lo, lo32, hl, ml, ll, ol);
        cur ^= 1;
    }

    // ---- epilogue: both q-tiles ----
    {
        const float inv = 1.0f / lh;
        const size_t rowoff = ((size_t)b * Tsz + qg_hi) * (size_t)Csz + (size_t)h * 128;
#pragma unroll
        for (int db = 0; db < 4; ++db)
#pragma unroll
            for (int gg = 0; gg < 4; ++gg) {
                unsigned w0 = cvt_pk_bf16(oh[db][4 * gg + 0] * inv, oh[db][4 * gg + 1] * inv);
                unsigned w1 = cvt_pk_bf16(oh[db][4 * gg + 2] * inv, oh[db][4 * gg + 3] * inv);
                u32x2 w = {w0, w1};
                *(u32x2*)(Y + rowoff + (db << 5) + (gg << 3) + (hl << 2)) = w;
            }
    }
    {
        const float inv = 1.0f / ll;
        const size_t rowoff = ((size_t)b * Tsz + qg_lo) * (size_t)Csz + (size_t)h * 128;
#pragma unroll
        for (int db = 0; db < 4; ++db)
#pragma unroll
            for (int gg = 0; gg < 4; ++gg) {
                unsigned w0 = cvt_pk_bf16(ol[db][4 * gg + 0] * inv, ol[db][4 * gg + 1] * inv);
                unsigned w1 = cvt_pk_bf16(ol[db][4 * gg + 2] * inv, ol[db][4 * gg + 3] * inv);
                u32x2 w = {w0, w1};
                *(u32x2*)(Y + rowoff + (db << 5) + (gg << 3) + (hl << 2)) = w;
            }
    }
}

extern "C" void kernel_launch(void* const* d_in, const int* in_sizes, int n_in,
                              void* d_out, int out_size, void* d_ws, size_t ws_size,
                              hipStream_t stream) {
    const float* x      = (const float*)d_in[0];
    const float* w_attn = (const float*)d_in[1];
    const float* w_proj = (const float*)d_in[2];
    float* out = (float*)d_out;

    char* ws = (char*)d_ws;
    bf16* Xb  = (bf16*)(ws);                 // 4096x2048           16 MB
    bf16* Wat = (bf16*)(ws + 16777216);      // 6144x2048 (W^T)     24 MB
    bf16* Wpt = (bf16*)(ws + 41943040);      // 2048x2048 (W^T)      8 MB
    bf16* Qr  = (bf16*)(ws + 50331648);      // [B,H,T,D] (scaled)  16 MB
    bf16* Kr  = (bf16*)(ws + 67108864);      // [B,H,T,D]           16 MB
    bf16* Vt  = (bf16*)(ws + 100663296);     // [B,H,D,T]           16 MB
    bf16* Yb  = (bf16*)(ws + 117440512);     // [B,T,C]             16 MB
    float2* cs = (float2*)(ws + 134217728);  // [T,64]               1 MB

    cast_x_kernel<<<4096, 256, 0, stream>>>(x, Xb, (Bsz * Tsz * Csz) / 8);
    transpose_cast_kernel<float><<<dim3(96, 32, 1), dim3(64, 4), 0, stream>>>(w_attn, Wat, 2048, 6144);
    transpose_cast_kernel<float><<<dim3(32, 32, 1), dim3(64, 4), 0, stream>>>(w_proj, Wpt, 2048, 2048);
    cossin_kernel<<<512, 256, 0, stream>>>(cs);

    gemm384_qkv<<<512, 512, 0, stream>>>(Xb, Wat, Qr, Kr, Vt, cs, 2048);

    attn_kernel<<<dim3(256), 256, 0, stream>>>(Qr, Kr, Vt, Yb);

    gemm256_proj<<<256, 512, 0, stream>>>(Yb, Wpt, out, 2048);
}

// Round 14
// 238.602 us; speedup vs baseline: 1.0580x; 1.0580x over previous
//
#include <hip/hip_runtime.h>
#include <hip/hip_bf16.h>
#include <math.h>

typedef __bf16 bf16;
typedef __bf16 bf16x8 __attribute__((ext_vector_type(8)));
typedef __bf16 bf16x4v __attribute__((ext_vector_type(4)));
typedef float f32x4 __attribute__((ext_vector_type(4)));
typedef float f32x16 __attribute__((ext_vector_type(16)));
typedef unsigned int u32x2 __attribute__((ext_vector_type(2)));
typedef unsigned int u32x4 __attribute__((ext_vector_type(4)));

#define MFMA16(a, b, c) __builtin_amdgcn_mfma_f32_16x16x32_bf16((a), (b), (c), 0, 0, 0)
#define MFMA32(a, b, c) __builtin_amdgcn_mfma_f32_32x32x16_bf16((a), (b), (c), 0, 0, 0)

static constexpr int Bsz = 2, Tsz = 2048, Csz = 2048, Hn = 16, Dh = 128;
static constexpr float ATTN_SCALE = 0.08838834764831845f; // 1/sqrt(128)

__device__ __forceinline__ void gld16(const void* src, void* dst) {
    __builtin_amdgcn_global_load_lds((__attribute__((address_space(1))) void*)src,
                                     (__attribute__((address_space(3))) void*)dst,
                                     16, 0, 0);
}

__device__ __forceinline__ unsigned cvt_pk_bf16(float lo, float hi) {
    unsigned r;
    asm("v_cvt_pk_bf16_f32 %0, %1, %2" : "=v"(r) : "v"(lo), "v"(hi));
    return r;
}

__device__ __forceinline__ bf16x8 make_pfrag(float p0, float p1, float p2, float p3,
                                             float p4, float p5, float p6, float p7) {
    unsigned a0 = cvt_pk_bf16(p0, p1), a1 = cvt_pk_bf16(p2, p3);
    unsigned b0 = cvt_pk_bf16(p4, p5), b1 = cvt_pk_bf16(p6, p7);
    asm volatile("v_permlane32_swap_b32 %0, %1" : "+v"(a0), "+v"(b0));
    asm volatile("v_permlane32_swap_b32 %0, %1" : "+v"(a1), "+v"(b1));
    u32x4 w = {a0, a1, b0, b1};
    return __builtin_bit_cast(bf16x8, w);
}

// ---------------- cast x (f32 -> bf16), 8 elems/thread ----------------
__global__ __launch_bounds__(256) void cast_x_kernel(const float* __restrict__ x,
                                                     bf16* __restrict__ o, int n8) {
    int i = blockIdx.x * 256 + threadIdx.x;
    if (i >= n8) return;
    const float4* x4 = (const float4*)x;
    float4 a = x4[2 * i], b = x4[2 * i + 1];
    bf16x8 v;
    v[0] = (bf16)a.x; v[1] = (bf16)a.y; v[2] = (bf16)a.z; v[3] = (bf16)a.w;
    v[4] = (bf16)b.x; v[5] = (bf16)b.y; v[6] = (bf16)b.z; v[7] = (bf16)b.w;
    ((bf16x8*)o)[i] = v;
}

// ---------------- tiled transpose-cast: out[c][r] = in[r][c], bf16x4 writes ----------------
template <typename TIN>
__global__ __launch_bounds__(256) void transpose_cast_kernel(const TIN* __restrict__ in,
                                                             bf16* __restrict__ out,
                                                             int R, int Cc) {
    __shared__ float tile[64][65];
    const int tx = threadIdx.x, ty = threadIdx.y;
    in  += (size_t)blockIdx.z * R * Cc;
    out += (size_t)blockIdx.z * R * Cc;
    const int c0 = blockIdx.x * 64, r0 = blockIdx.y * 64;
#pragma unroll
    for (int j = 0; j < 16; ++j) {
        int rr = ty + j * 4;
        tile[rr][tx] = (float)in[(size_t)(r0 + rr) * Cc + c0 + tx];
    }
    __syncthreads();
    const int q = (tx & 15) << 2;  // row-quad base
    const int cg = tx >> 4;        // col-group [0,4)
#pragma unroll
    for (int j = 0; j < 4; ++j) {
        const int cc = j * 16 + cg * 4 + ty;
        bf16x4v v;
        v[0] = (bf16)tile[q + 0][cc];
        v[1] = (bf16)tile[q + 1][cc];
        v[2] = (bf16)tile[q + 2][cc];
        v[3] = (bf16)tile[q + 3][cc];
        *(bf16x4v*)(out + (size_t)(c0 + cc) * R + r0 + q) = v;
    }
}

// ---------------- rope cos/sin table ----------------
__global__ __launch_bounds__(256) void cossin_kernel(float2* __restrict__ cs) {
    int idx = blockIdx.x * 256 + threadIdx.x; // 2048*64
    int t = idx >> 6, i = idx & 63;
    float theta = 1.0f / powf(10000.0f, (float)(2 * i) / 128.0f);
    float ang = (float)t * theta;
    cs[idx] = make_float2(cosf(ang), sinf(ang));
}

// =============== 128x384 GEMM, deep counted-vmcnt pipeline (round-5/8 best) ===============
// Fused epilogue: rope+head-split for Q/K; V written DIRECTLY as V^T [B,H,D,T].
__global__ __launch_bounds__(512, 2)
void gemm384_qkv(const bf16* __restrict__ A, const bf16* __restrict__ Bt,
                 bf16* __restrict__ Oq, bf16* __restrict__ Ok, bf16* __restrict__ Vt,
                 const float2* __restrict__ cs, int K) {
    __shared__ bf16 sA[2][128 * 64];
    __shared__ bf16 sB[2][384 * 64];
    const int tid = threadIdx.x, lane = tid & 63, wid = tid >> 6;
    const int wm = wid >> 2, wn = wid & 3;
    const int lo16 = lane & 15, hi4 = lane >> 4;

    const int cpx = gridDim.x >> 3;
    const int swz = (blockIdx.x & 7) * cpx + (blockIdx.x >> 3);
    const int by = swz & 31;   // M/128 = 32
    const int bx = swz >> 5;   // N/384 = 16
    const int row0 = by << 7, col0 = bx * 384;

    const int srow = tid >> 3;                                   // [0,64)
    const int swzoff = (((tid & 7) ^ ((tid >> 3) & 7)) << 3);    // elements
    const bf16* srcA = A  + (size_t)(row0 + srow) * K + swzoff;
    const bf16* srcB = Bt + (size_t)(col0 + srow) * K + swzoff;
    const size_t K64 = (size_t)K * 64;
    char* const ldsA = (char*)&sA[0][0];
    char* const ldsB = (char*)&sB[0][0];
    const int wuo = wid << 10;

    auto issueA = [&](int c, int kt) {   // A tile 128x64 = 16KB
        const bf16* s = srcA + (size_t)kt * 64;
        gld16(s,       ldsA + c * 16384 + 0    + wuo);
        gld16(s + K64, ldsA + c * 16384 + 8192 + wuo);
    };
    auto issueB = [&](int c, int kt, int u) { // B rows [128u, 128u+128) = 16KB
        const bf16* s = srcB + (size_t)kt * 64 + (size_t)(2 * u) * K64;
        gld16(s,       ldsB + c * 49152 + u * 16384 + 0    + wuo);
        gld16(s + K64, ldsB + c * 49152 + u * 16384 + 8192 + wuo);
    };
    auto ldF = [&](const char* buf, int row, int ks) {
        return *(const bf16x8*)(buf + row * 128 + ((((ks << 2) + hi4) ^ (row & 7)) << 4));
    };

    const int arow = (wm << 6) + lo16;   // + mi*16, mi in [0,4)
    const int brow = (wn << 4) + lo16;   // + nj*64, nj in [0,6)

    f32x4 acc[4][6] = {};
    const int nkt = K >> 6;

    issueA(0, 0); issueB(0, 0, 0); issueB(0, 0, 1); issueB(0, 0, 2);
    asm volatile("s_waitcnt vmcnt(4)" ::: "memory");
    __builtin_amdgcn_s_barrier();

    for (int kt = 0; kt < nkt - 1; ++kt) {
        const int c = kt & 1;
        const char* bufA = ldsA + c * 16384;
        const char* bufB = ldsB + c * 49152;
        bf16x8 af[4][2], bq[2][2];
        // ---- phase 0: nj {0,1} ----
#pragma unroll
        for (int i = 0; i < 4; ++i) {
            af[i][0] = ldF(bufA, arow + (i << 4), 0);
            af[i][1] = ldF(bufA, arow + (i << 4), 1);
        }
#pragma unroll
        for (int j = 0; j < 2; ++j) {
            bq[j][0] = ldF(bufB, brow + (j << 6), 0);
            bq[j][1] = ldF(bufB, brow + (j << 6), 1);
        }
        issueA(c ^ 1, kt + 1); issueB(c ^ 1, kt + 1, 0); issueB(c ^ 1, kt + 1, 1);
        __builtin_amdgcn_s_barrier();
        asm volatile("s_waitcnt lgkmcnt(0)" ::: "memory");
        __builtin_amdgcn_sched_barrier(0);
        __builtin_amdgcn_s_setprio(1);
#pragma unroll
        for (int ks = 0; ks < 2; ++ks)
#pragma unroll
            for (int i = 0; i < 4; ++i)
#pragma unroll
                for (int j = 0; j < 2; ++j)
                    acc[i][j] = MFMA16(af[i][ks], bq[j][ks], acc[i][j]);
        __builtin_amdgcn_s_setprio(0);
        asm volatile("s_waitcnt vmcnt(8)" ::: "memory"); // B-b(kt) landed
        __builtin_amdgcn_s_barrier();
        // ---- phase 1: nj {2,3} ----
#pragma unroll
        for (int j = 0; j < 2; ++j) {
            bq[j][0] = ldF(bufB, brow + ((j + 2) << 6), 0);
            bq[j][1] = ldF(bufB, brow + ((j + 2) << 6), 1);
        }
        issueB(c ^ 1, kt + 1, 2);
        __builtin_amdgcn_s_barrier();
        asm volatile("s_waitcnt lgkmcnt(0)" ::: "memory");
        __builtin_amdgcn_sched_barrier(0);
        __builtin_amdgcn_s_setprio(1);
#pragma unroll
        for (int ks = 0; ks < 2; ++ks)
#pragma unroll
            for (int i = 0; i < 4; ++i)
#pragma unroll
                for (int j = 0; j < 2; ++j)
                    acc[i][j + 2] = MFMA16(af[i][ks], bq[j][ks], acc[i][j + 2]);
        __builtin_amdgcn_s_setprio(0);
        asm volatile("s_waitcnt vmcnt(8)" ::: "memory"); // B-c(kt) landed
        __builtin_amdgcn_s_barrier();
        // ---- phase 2: nj {4,5} ----
#pragma unroll
        for (int j = 0; j < 2; ++j) {
            bq[j][0] = ldF(bufB, brow + ((j + 4) << 6), 0);
            bq[j][1] = ldF(bufB, brow + ((j + 4) << 6), 1);
        }
        __builtin_amdgcn_s_barrier();
        asm volatile("s_waitcnt lgkmcnt(0)" ::: "memory");
        __builtin_amdgcn_sched_barrier(0);
        __builtin_amdgcn_s_setprio(1);
#pragma unroll
        for (int ks = 0; ks < 2; ++ks)
#pragma unroll
            for (int i = 0; i < 4; ++i)
#pragma unroll
                for (int j = 0; j < 2; ++j)
                    acc[i][j + 4] = MFMA16(af[i][ks], bq[j][ks], acc[i][j + 4]);
        __builtin_amdgcn_s_setprio(0);
        asm volatile("s_waitcnt vmcnt(4)" ::: "memory"); // A(kt+1), B-a(kt+1) landed
        __builtin_amdgcn_s_barrier();
    }

    { // ---- peeled last tile ----
        const int c = (nkt - 1) & 1;
        const char* bufA = ldsA + c * 16384;
        const char* bufB = ldsB + c * 49152;
        bf16x8 af[4][2], bq[2][2];
#pragma unroll
        for (int i = 0; i < 4; ++i) {
            af[i][0] = ldF(bufA, arow + (i << 4), 0);
            af[i][1] = ldF(bufA, arow + (i << 4), 1);
        }
#pragma unroll
        for (int j = 0; j < 2; ++j) {
            bq[j][0] = ldF(bufB, brow + (j << 6), 0);
            bq[j][1] = ldF(bufB, brow + (j << 6), 1);
        }
        __builtin_amdgcn_s_barrier();
        asm volatile("s_waitcnt lgkmcnt(0)" ::: "memory");
        __builtin_amdgcn_sched_barrier(0);
        __builtin_amdgcn_s_setprio(1);
#pragma unroll
        for (int ks = 0; ks < 2; ++ks)
#pragma unroll
            for (int i = 0; i < 4; ++i)
#pragma unroll
                for (int j = 0; j < 2; ++j)
                    acc[i][j] = MFMA16(af[i][ks], bq[j][ks], acc[i][j]);
        __builtin_amdgcn_s_setprio(0);
        asm volatile("s_waitcnt vmcnt(2)" ::: "memory");
        __builtin_amdgcn_s_barrier();
#pragma unroll
        for (int j = 0; j < 2; ++j) {
            bq[j][0] = ldF(bufB, brow + ((j + 2) << 6), 0);
            bq[j][1] = ldF(bufB, brow + ((j + 2) << 6), 1);
        }
        __builtin_amdgcn_s_barrier();
        asm volatile("s_waitcnt lgkmcnt(0)" ::: "memory");
        __builtin_amdgcn_sched_barrier(0);
        __builtin_amdgcn_s_setprio(1);
#pragma unroll
        for (int ks = 0; ks < 2; ++ks)
#pragma unroll
            for (int i = 0; i < 4; ++i)
#pragma unroll
                for (int j = 0; j < 2; ++j)
                    acc[i][j + 2] = MFMA16(af[i][ks], bq[j][ks], acc[i][j + 2]);
        __builtin_amdgcn_s_setprio(0);
        asm volatile("s_waitcnt vmcnt(0)" ::: "memory");
        __builtin_amdgcn_s_barrier();
#pragma unroll
        for (int j = 0; j < 2; ++j) {
            bq[j][0] = ldF(bufB, brow + ((j + 4) << 6), 0);
            bq[j][1] = ldF(bufB, brow + ((j + 4) << 6), 1);
        }
        __builtin_amdgcn_s_barrier();
        asm volatile("s_waitcnt lgkmcnt(0)" ::: "memory");
        __builtin_amdgcn_sched_barrier(0);
        __builtin_amdgcn_s_setprio(1);
#pragma unroll
        for (int ks = 0; ks < 2; ++ks)
#pragma unroll
            for (int i = 0; i < 4; ++i)
#pragma unroll
                for (int j = 0; j < 2; ++j)
                    acc[i][j + 4] = MFMA16(af[i][ks], bq[j][ks], acc[i][j + 4]);
        __builtin_amdgcn_s_setprio(0);
    }

    // ---- epilogue: rope + head split (Q/K); direct V^T write (V) ----
    const int d = (wn << 4) + lo16; // [0,64)
#pragma unroll
    for (int p = 0; p < 3; ++p) {
        const int gcb = col0 + (p << 7);
        const int seg = gcb >> 11;            // 0=q 1=k 2=v
        const int hb = (gcb >> 7) & 15;
        if (seg < 2) {
            bf16* dst0 = (seg == 0) ? Oq : Ok;
            const float qs = (seg == 0) ? ATTN_SCALE : 1.0f;
#pragma unroll
            for (int mi = 0; mi < 4; ++mi)
#pragma unroll
                for (int r = 0; r < 4; ++r) {
                    const int gm = row0 + (wm << 6) + (mi << 4) + (hi4 << 2) + r;
                    const int b = gm >> 11, t = gm & 2047;
                    const float2 csv = cs[t * 64 + d];
                    bf16* drow = dst0 + ((((size_t)b * Hn + hb) * Tsz + t) << 7);
                    const float vlo = acc[mi][2 * p][r];
                    const float vhi = acc[mi][2 * p + 1][r];
                    drow[d]      = (bf16)((vlo * csv.x - vhi * csv.y) * qs);
                    drow[d + 64] = (bf16)((vhi * csv.x + vlo * csv.y) * qs);
                }
        } else {
            // V^T [B,H,D,T]: r=0..3 are consecutive t -> one u32x2 (4 bf16) per d
#pragma unroll
            for (int mi = 0; mi < 4; ++mi) {
                const int t0 = row0 + (wm << 6) + (mi << 4) + (hi4 << 2);
                const int b = t0 >> 11, tt = t0 & 2047;
                bf16* vbase = Vt + (((size_t)b * Hn + hb) * Dh) * Tsz + tt;
                u32x2 wlo = {cvt_pk_bf16(acc[mi][2 * p][0], acc[mi][2 * p][1]),
                             cvt_pk_bf16(acc[mi][2 * p][2], acc[mi][2 * p][3])};
                u32x2 whi = {cvt_pk_bf16(acc[mi][2 * p + 1][0], acc[mi][2 * p + 1][1]),
                             cvt_pk_bf16(acc[mi][2 * p + 1][2], acc[mi][2 * p + 1][3])};
                *(u32x2*)(vbase + (size_t)d * Tsz)        = wlo;
                *(u32x2*)(vbase + (size_t)(d + 64) * Tsz) = whi;
            }
        }
    }
}

// =============== 128x256 output-projection GEMM, MFMA32 (2M x 4N waves) ===============
// Per-wave 64x64 = 2x2 frags of 32x32; A/B operand layout and C/D mapping
// hardware-validated by the attn kernel (same intrinsic, same patterns).
// Staging/schedule identical to round-8 counted 2-phase.
__global__ __launch_bounds__(512, 2)
void gemm256_proj(const bf16* __restrict__ A, const bf16* __restrict__ Bt,
                  float* __restrict__ Cf, int K) {
    __shared__ bf16 sA[2][128 * 64];
    __shared__ bf16 sB[2][256 * 64];
    const int tid = threadIdx.x, lane = tid & 63, wid = tid >> 6;
    const int wm = wid >> 2, wn = wid & 3;   // 2M x 4N
    const int lo32 = lane & 31, hl = lane >> 5;
    const int N = 2048;

    const int cpx = gridDim.x >> 3;
    const int swz = (blockIdx.x & 7) * cpx + (blockIdx.x >> 3);
    const int by = swz & 31;   // M/128 = 32
    const int bx = swz >> 5;   // N/256 = 8
    const int row0 = by << 7, col0 = bx << 8;

    const int srow = tid >> 3;
    const int swzoff = (((tid & 7) ^ ((tid >> 3) & 7)) << 3);
    const bf16* srcA = A  + (size_t)(row0 + srow) * K + swzoff;
    const bf16* srcB = Bt + (size_t)(col0 + srow) * K + swzoff;
    const size_t K64 = (size_t)K * 64;
    char* const ldsA = (char*)&sA[0][0];
    char* const ldsB = (char*)&sB[0][0];
    const int wuo = wid << 10;

    auto issueA = [&](int c, int kt) {
        const bf16* s = srcA + (size_t)kt * 64;
        gld16(s,       ldsA + c * 16384 + 0    + wuo);
        gld16(s + K64, ldsA + c * 16384 + 8192 + wuo);
    };
    auto issueB = [&](int c, int kt, int u) { // B rows [128u, 128u+128)
        const bf16* s = srcB + (size_t)kt * 64 + (size_t)(2 * u) * K64;
        gld16(s,       ldsB + c * 32768 + u * 16384 + 0    + wuo);
        gld16(s + K64, ldsB + c * 32768 + u * 16384 + 8192 + wuo);
    };
    // MFMA32 operand frag: row = lane&31 (+frag base), k = 16*ks16 + 8*hl + j
    auto ldF32 = [&](const char* buf, int row, int ks16) {
        return *(const bf16x8*)(buf + row * 128 + ((((ks16 << 1) + hl) ^ (row & 7)) << 4));
    };

    const int arow = (wm << 6) + lo32;   // + mf*32, mf in {0,1}
    const int brow = (wn << 6) + lo32;   // + nf*32, nf in {0,1}

    f32x16 acc[2][2] = {};
    const int nkt = K >> 6;

    issueA(0, 0); issueB(0, 0, 0); issueB(0, 0, 1);
    if (nkt > 1) { issueA(1, 1); issueB(1, 1, 0); }
    asm volatile("s_waitcnt vmcnt(4)" ::: "memory");
    __builtin_amdgcn_s_barrier();

    for (int kt = 0; kt < nkt; ++kt) {
        const int c = kt & 1;
        const char* bufA = ldsA + c * 16384;
        const char* bufB = ldsB + c * 32768;
        bf16x8 af[2][4], bq[4];
        // ---- phase 0: nf=0 (+ all A frags for the K-tile) ----
#pragma unroll
        for (int mf = 0; mf < 2; ++mf)
#pragma unroll
            for (int ks = 0; ks < 4; ++ks)
                af[mf][ks] = ldF32(bufA, arow + (mf << 5), ks);
#pragma unroll
        for (int ks = 0; ks < 4; ++ks)
            bq[ks] = ldF32(bufB, brow, ks);
        if (kt + 1 < nkt) issueB(c ^ 1, kt + 1, 1);   // Bb(kt+1)
        __builtin_amdgcn_s_barrier();
        asm volatile("s_waitcnt lgkmcnt(0)" ::: "memory");
        __builtin_amdgcn_sched_barrier(0);
        __builtin_amdgcn_s_setprio(1);
#pragma unroll
        for (int ks = 0; ks < 4; ++ks)
#pragma unroll
            for (int mf = 0; mf < 2; ++mf)
                acc[mf][0] = MFMA32(af[mf][ks], bq[ks], acc[mf][0]);
        __builtin_amdgcn_s_setprio(0);
        if (kt + 1 < nkt) asm volatile("s_waitcnt vmcnt(6)" ::: "memory");
        else              asm volatile("s_waitcnt vmcnt(0)" ::: "memory");
        __builtin_amdgcn_s_barrier();
        // ---- phase 1: nf=1 ----
#pragma unroll
        for (int ks = 0; ks < 4; ++ks)
            bq[ks] = ldF32(bufB, brow + 32, ks);
        if (kt + 2 < nkt) { issueA(c, kt + 2); issueB(c, kt + 2, 0); }
        __builtin_amdgcn_s_barrier();
        asm volatile("s_waitcnt lgkmcnt(0)" ::: "memory");
        __builtin_amdgcn_sched_barrier(0);
        __builtin_amdgcn_s_setprio(1);
#pragma unroll
        for (int ks = 0; ks < 4; ++ks)
#pragma unroll
            for (int mf = 0; mf < 2; ++mf)
                acc[mf][1] = MFMA32(af[mf][ks], bq[ks], acc[mf][1]);
        __builtin_amdgcn_s_setprio(0);
        if (kt + 2 < nkt)      asm volatile("s_waitcnt vmcnt(6)" ::: "memory");
        else if (kt + 1 < nkt) asm volatile("s_waitcnt vmcnt(2)" ::: "memory");
        __builtin_amdgcn_s_barrier();
    }

    // ---- epilogue: f32 C write. C/D: row=(r&3)+8*(r>>2)+4*hl, col=lane&31 ----
#pragma unroll
    for (int mf = 0; mf < 2; ++mf)
#pragma unroll
        for (int r = 0; r < 16; ++r) {
            const int gm = row0 + (wm << 6) + (mf << 5) + (r & 3) + ((r >> 2) << 3) + (hl << 2);
            float* crow = Cf + (size_t)gm * N + col0 + (wn << 6) + lo32;
            crow[0]  = acc[mf][0][r];
            crow[32] = acc[mf][1][r];
        }
}

// ---------------- flash attention: 4 waves x 32 q-rows (QBLK=128), KVBLK=64 ----
// (round-12 version: 512 blocks paired (t,15-t), 2 blocks/CU, XCD-local bh)
__device__ __forceinline__ void stage_tile(const bf16* __restrict__ Kb,
                                           const bf16* __restrict__ Vtb,
                                           bf16* sKc, bf16* sVc, int k0, int tid) {
#pragma unroll
    for (int c = 0; c < 4; ++c) {
        const int off = (c << 12) + (tid << 4);
        const int row = off >> 8, u = (off >> 4) & 15;
        gld16(Kb + (size_t)(k0 + row) * Dh + ((u ^ (row & 7)) << 3), (char*)sKc + off);
        const int dv = off >> 7, uv = (off >> 4) & 7;
        gld16(Vtb + (size_t)dv * Tsz + k0 + ((uv ^ (dv & 7)) << 3), (char*)sVc + off);
    }
}

__global__ __launch_bounds__(256, 2)
void attn_kernel(const bf16* __restrict__ Q, const bf16* __restrict__ K,
                 const bf16* __restrict__ Vt, bf16* __restrict__ Y) {
    __shared__ bf16 sK[2][64 * 128];
    __shared__ bf16 sV[2][128 * 64];
    const int tid = threadIdx.x, lane = tid & 63, wv = tid >> 6;
    const int lo32 = lane & 31, hl = lane >> 5;

    const int i = blockIdx.x;
    const int g = i >> 5;
    const int bh = i & 31;
    const int t = (i < 256) ? (15 - g) : (g - 8);
    const int b = bh >> 4, h = bh & 15;

    const int q0 = t << 7;
    const int q0w = q0 + (wv << 5);
    const int qg = q0w + lo32;

    const bf16* Kb  = K  + (size_t)bh * (Tsz * Dh);
    const bf16* Vtb = Vt + (size_t)bh * (Tsz * Dh);
    const bf16* Qp  = Q  + (size_t)bh * (Tsz * Dh) + (size_t)qg * Dh;

    bf16x8 qf[8];
#pragma unroll
    for (int kc = 0; kc < 8; ++kc)
        qf[kc] = *(const bf16x8*)(Qp + (kc << 4) + (hl << 3));

    float m = -1e30f, lsum = 0.f;
    f32x16 o[4] = {};

    const int nt_block = 2 * t + 2;
    const int nt_warp = ((q0w + 31) >> 6) + 1;

    stage_tile(Kb, Vtb, &sK[0][0], &sV[0][0], 0, tid);

    int cur = 0;
    for (int kt = 0; kt < nt_block; ++kt) {
        __syncthreads();
        if (kt + 1 < nt_block)
            stage_tile(Kb, Vtb, &sK[cur ^ 1][0], &sV[cur ^ 1][0], (kt + 1) << 6, tid);
        if (kt < nt_warp) {
            const int k0 = kt << 6;
            const bf16* kbuf = &sK[cur][0];
            const bf16* vbuf = &sV[cur][0];
            f32x16 s0 = {}, s1 = {};
            const int swk = lo32 & 7;
            __builtin_amdgcn_s_setprio(1);
#pragma unroll
            for (int kc = 0; kc < 8; ++kc) {
                bf16x8 kf0 = *(const bf16x8*)((const char*)kbuf + lo32 * 256 +
                              ((((kc << 1) + hl) ^ swk) << 4));
                s0 = MFMA32(kf0, qf[kc], s0);
                bf16x8 kf1 = *(const bf16x8*)((const char*)kbuf + (32 + lo32) * 256 +
                              ((((kc << 1) + hl) ^ swk) << 4));
                s1 = MFMA32(kf1, qf[kc], s1);
            }
            __builtin_amdgcn_s_setprio(0);

            const bool bnd = (k0 + 63 > q0w);
            if (bnd) {
#pragma unroll
                for (int r = 0; r < 16; ++r) {
                    const int kl = (r & 3) + ((r >> 2) << 3) + (hl << 2);
                    if (k0 + kl > qg)      s0[r] = -1e30f;
                    if (k0 + 32 + kl > qg) s1[r] = -1e30f;
                }
            }
            float pm = s0[0];
#pragma unroll
            for (int r = 1; r < 16; ++r) pm = fmaxf(pm, s0[r]);
#pragma unroll
            for (int r = 0; r < 16; ++r) pm = fmaxf(pm, s1[r]);
            pm = fmaxf(pm, __shfl_xor(pm, 32));

            if (__any(pm > m + 8.0f)) {
                const float mn = fmaxf(m, pm);
                const float sc = __expf(m - mn);
                m = mn;
                lsum *= sc;
#pragma unroll
                for (int db = 0; db < 4; ++db)
#pragma unroll
                    for (int r = 0; r < 16; ++r) o[db][r] *= sc;
            }
            float rs = 0.f;
            if (bnd) {
#pragma unroll
                for (int r = 0; r < 16; ++r) {
                    float e0 = (s0[r] > -1e29f) ? __expf(s0[r] - m) : 0.f;
                    float e1 = (s1[r] > -1e29f) ? __expf(s1[r] - m) : 0.f;
                    s0[r] = e0; s1[r] = e1; rs += e0 + e1;
                }
            } else {
#pragma unroll
                for (int r = 0; r < 16; ++r) {
                    float e0 = __expf(s0[r] - m);
                    float e1 = __expf(s1[r] - m);
                    s0[r] = e0; s1[r] = e1; rs += e0 + e1;
                }
            }
            rs += __shfl_xor(rs, 32);
            lsum += rs;

            bf16x8 pb0 = make_pfrag(s0[0], s0[1], s0[2],  s0[3],  s0[4],  s0[5],  s0[6],  s0[7]);
            bf16x8 pb1 = make_pfrag(s0[8], s0[9], s0[10], s0[11], s0[12], s0[13], s0[14], s0[15]);
            bf16x8 pb2 = make_pfrag(s1[0], s1[1], s1[2],  s1[3],  s1[4],  s1[5],  s1[6],  s1[7]);
            bf16x8 pb3 = make_pfrag(s1[8], s1[9], s1[10], s1[11], s1[12], s1[13], s1[14], s1[15]);

            __builtin_amdgcn_s_setprio(1);
#pragma unroll
            for (int db = 0; db < 4; ++db) {
                const int rd = (db << 5) + lo32;
                const char* vrow = (const char*)vbuf + rd * 128;
                const int sw = rd & 7;
                bf16x8 v0 = *(const bf16x8*)(vrow + (((0 + hl) ^ sw) << 4));
                o[db] = MFMA32(v0, pb0, o[db]);
                bf16x8 v1 = *(const bf16x8*)(vrow + (((2 + hl) ^ sw) << 4));
                o[db] = MFMA32(v1, pb1, o[db]);
                bf16x8 v2 = *(const bf16x8*)(vrow + (((4 + hl) ^ sw) << 4));
                o[db] = MFMA32(v2, pb2, o[db]);
                bf16x8 v3 = *(const bf16x8*)(vrow + (((6 + hl) ^ sw) << 4));
                o[db] = MFMA32(v3, pb3, o[db]);
            }
            __builtin_amdgcn_s_setprio(0);
        }
        cur ^= 1;
    }

    const float inv = 1.0f / lsum;
    const size_t rowoff = ((size_t)b * Tsz + qg) * (size_t)Csz + (size_t)h * 128;
#pragma unroll
    for (int db = 0; db < 4; ++db)
#pragma unroll
        for (int gg = 0; gg < 4; ++gg) {
            unsigned w0 = cvt_pk_bf16(o[db][4 * gg + 0] * inv, o[db][4 * gg + 1] * inv);
            unsigned w1 = cvt_pk_bf16(o[db][4 * gg + 2] * inv, o[db][4 * gg + 3] * inv);
            u32x2 w = {w0, w1};
            *(u32x2*)(Y + rowoff + (db << 5) + (gg << 3) + (hl << 2)) = w;
        }
}

extern "C" void kernel_launch(void* const* d_in, const int* in_sizes, int n_in,
                              void* d_out, int out_size, void* d_ws, size_t ws_size,
                              hipStream_t stream) {
    const float* x      = (const float*)d_in[0];
    const float* w_attn = (const float*)d_in[1];
    const float* w_proj = (const float*)d_in[2];
    float* out = (float*)d_out;

    char* ws = (char*)d_ws;
    bf16* Xb  = (bf16*)(ws);                 // 4096x2048           16 MB
    bf16* Wat = (bf16*)(ws + 16777216);      // 6144x2048 (W^T)     24 MB
    bf16* Wpt = (bf16*)(ws + 41943040);      // 2048x2048 (W^T)      8 MB
    bf16* Qr  = (bf16*)(ws + 50331648);      // [B,H,T,D] (scaled)  16 MB
    bf16* Kr  = (bf16*)(ws + 67108864);      // [B,H,T,D]           16 MB
    bf16* Vt  = (bf16*)(ws + 100663296);     // [B,H,D,T]           16 MB
    bf16* Yb  = (bf16*)(ws + 117440512);     // [B,T,C]             16 MB
    float2* cs = (float2*)(ws + 134217728);  // [T,64]               1 MB

    cast_x_kernel<<<4096, 256, 0, stream>>>(x, Xb, (Bsz * Tsz * Csz) / 8);
    transpose_cast_kernel<float><<<dim3(96, 32, 1), dim3(64, 4), 0, stream>>>(w_attn, Wat, 2048, 6144);
    transpose_cast_kernel<float><<<dim3(32, 32, 1), dim3(64, 4), 0, stream>>>(w_proj, Wpt, 2048, 2048);
    cossin_kernel<<<512, 256, 0, stream>>>(cs);

    gemm384_qkv<<<512, 512, 0, stream>>>(Xb, Wat, Qr, Kr, Vt, cs, 2048);

    attn_kernel<<<dim3(512), 256, 0, stream>>>(Qr, Kr, Vt, Yb);

    gemm256_proj<<<256, 512, 0, stream>>>(Yb, Wpt, out, 2048);
}

// Round 15
// 234.167 us; speedup vs baseline: 1.0780x; 1.0189x over previous
//
#include <hip/hip_runtime.h>
#include <hip/hip_bf16.h>
#include <math.h>

typedef __bf16 bf16;
typedef __bf16 bf16x8 __attribute__((ext_vector_type(8)));
typedef __bf16 bf16x4v __attribute__((ext_vector_type(4)));
typedef float f32x4 __attribute__((ext_vector_type(4)));
typedef float f32x16 __attribute__((ext_vector_type(16)));
typedef unsigned int u32x2 __attribute__((ext_vector_type(2)));
typedef unsigned int u32x4 __attribute__((ext_vector_type(4)));

#define MFMA16(a, b, c) __builtin_amdgcn_mfma_f32_16x16x32_bf16((a), (b), (c), 0, 0, 0)
#define MFMA32(a, b, c) __builtin_amdgcn_mfma_f32_32x32x16_bf16((a), (b), (c), 0, 0, 0)

static constexpr int Bsz = 2, Tsz = 2048, Csz = 2048, Hn = 16, Dh = 128;
static constexpr float ATTN_SCALE = 0.08838834764831845f; // 1/sqrt(128)

__device__ __forceinline__ void gld16(const void* src, void* dst) {
    __builtin_amdgcn_global_load_lds((__attribute__((address_space(1))) void*)src,
                                     (__attribute__((address_space(3))) void*)dst,
                                     16, 0, 0);
}

__device__ __forceinline__ unsigned cvt_pk_bf16(float lo, float hi) {
    unsigned r;
    asm("v_cvt_pk_bf16_f32 %0, %1, %2" : "=v"(r) : "v"(lo), "v"(hi));
    return r;
}

__device__ __forceinline__ bf16x8 make_pfrag(float p0, float p1, float p2, float p3,
                                             float p4, float p5, float p6, float p7) {
    unsigned a0 = cvt_pk_bf16(p0, p1), a1 = cvt_pk_bf16(p2, p3);
    unsigned b0 = cvt_pk_bf16(p4, p5), b1 = cvt_pk_bf16(p6, p7);
    asm volatile("v_permlane32_swap_b32 %0, %1" : "+v"(a0), "+v"(b0));
    asm volatile("v_permlane32_swap_b32 %0, %1" : "+v"(a1), "+v"(b1));
    u32x4 w = {a0, a1, b0, b1};
    return __builtin_bit_cast(bf16x8, w);
}

// ---------------- fused: cast x (f32->bf16, 8/thread) + rope cos/sin table ----------------
__global__ __launch_bounds__(256) void prep_kernel(const float* __restrict__ x,
                                                   bf16* __restrict__ o,
                                                   float2* __restrict__ cs, int n8) {
    const int bid = blockIdx.x;
    if (bid < 4096) {
        int i = bid * 256 + threadIdx.x;
        if (i >= n8) return;
        const float4* x4 = (const float4*)x;
        float4 a = x4[2 * i], b = x4[2 * i + 1];
        bf16x8 v;
        v[0] = (bf16)a.x; v[1] = (bf16)a.y; v[2] = (bf16)a.z; v[3] = (bf16)a.w;
        v[4] = (bf16)b.x; v[5] = (bf16)b.y; v[6] = (bf16)b.z; v[7] = (bf16)b.w;
        ((bf16x8*)o)[i] = v;
    } else {
        int idx = (bid - 4096) * 256 + threadIdx.x; // 2048*64
        int t = idx >> 6, i = idx & 63;
        float theta = 1.0f / powf(10000.0f, (float)(2 * i) / 128.0f);
        float ang = (float)t * theta;
        cs[idx] = make_float2(cosf(ang), sinf(ang));
    }
}

// ---------------- tiled transpose-cast: out[c][r] = in[r][c], bf16x4 writes ----------------
template <typename TIN>
__global__ __launch_bounds__(256) void transpose_cast_kernel(const TIN* __restrict__ in,
                                                             bf16* __restrict__ out,
                                                             int R, int Cc) {
    __shared__ float tile[64][65];
    const int tx = threadIdx.x, ty = threadIdx.y;
    in  += (size_t)blockIdx.z * R * Cc;
    out += (size_t)blockIdx.z * R * Cc;
    const int c0 = blockIdx.x * 64, r0 = blockIdx.y * 64;
#pragma unroll
    for (int j = 0; j < 16; ++j) {
        int rr = ty + j * 4;
        tile[rr][tx] = (float)in[(size_t)(r0 + rr) * Cc + c0 + tx];
    }
    __syncthreads();
    const int q = (tx & 15) << 2;  // row-quad base
    const int cg = tx >> 4;        // col-group [0,4)
#pragma unroll
    for (int j = 0; j < 4; ++j) {
        const int cc = j * 16 + cg * 4 + ty;
        bf16x4v v;
        v[0] = (bf16)tile[q + 0][cc];
        v[1] = (bf16)tile[q + 1][cc];
        v[2] = (bf16)tile[q + 2][cc];
        v[3] = (bf16)tile[q + 3][cc];
        *(bf16x4v*)(out + (size_t)(c0 + cc) * R + r0 + q) = v;
    }
}

// =============== 128x384 GEMM, deep counted-vmcnt pipeline (round-5/8 best) ===============
// Fused epilogue: rope+head-split for Q/K; V written DIRECTLY as V^T [B,H,D,T].
__global__ __launch_bounds__(512, 2)
void gemm384_qkv(const bf16* __restrict__ A, const bf16* __restrict__ Bt,
                 bf16* __restrict__ Oq, bf16* __restrict__ Ok, bf16* __restrict__ Vt,
                 const float2* __restrict__ cs, int K) {
    __shared__ bf16 sA[2][128 * 64];
    __shared__ bf16 sB[2][384 * 64];
    const int tid = threadIdx.x, lane = tid & 63, wid = tid >> 6;
    const int wm = wid >> 2, wn = wid & 3;
    const int lo16 = lane & 15, hi4 = lane >> 4;

    const int cpx = gridDim.x >> 3;
    const int swz = (blockIdx.x & 7) * cpx + (blockIdx.x >> 3);
    const int by = swz & 31;   // M/128 = 32
    const int bx = swz >> 5;   // N/384 = 16
    const int row0 = by << 7, col0 = bx * 384;

    const int srow = tid >> 3;                                   // [0,64)
    const int swzoff = (((tid & 7) ^ ((tid >> 3) & 7)) << 3);    // elements
    const bf16* srcA = A  + (size_t)(row0 + srow) * K + swzoff;
    const bf16* srcB = Bt + (size_t)(col0 + srow) * K + swzoff;
    const size_t K64 = (size_t)K * 64;
    char* const ldsA = (char*)&sA[0][0];
    char* const ldsB = (char*)&sB[0][0];
    const int wuo = wid << 10;

    auto issueA = [&](int c, int kt) {   // A tile 128x64 = 16KB
        const bf16* s = srcA + (size_t)kt * 64;
        gld16(s,       ldsA + c * 16384 + 0    + wuo);
        gld16(s + K64, ldsA + c * 16384 + 8192 + wuo);
    };
    auto issueB = [&](int c, int kt, int u) { // B rows [128u, 128u+128) = 16KB
        const bf16* s = srcB + (size_t)kt * 64 + (size_t)(2 * u) * K64;
        gld16(s,       ldsB + c * 49152 + u * 16384 + 0    + wuo);
        gld16(s + K64, ldsB + c * 49152 + u * 16384 + 8192 + wuo);
    };
    auto ldF = [&](const char* buf, int row, int ks) {
        return *(const bf16x8*)(buf + row * 128 + ((((ks << 2) + hi4) ^ (row & 7)) << 4));
    };

    const int arow = (wm << 6) + lo16;   // + mi*16, mi in [0,4)
    const int brow = (wn << 4) + lo16;   // + nj*64, nj in [0,6)

    f32x4 acc[4][6] = {};
    const int nkt = K >> 6;

    issueA(0, 0); issueB(0, 0, 0); issueB(0, 0, 1); issueB(0, 0, 2);
    asm volatile("s_waitcnt vmcnt(4)" ::: "memory");
    __builtin_amdgcn_s_barrier();

    for (int kt = 0; kt < nkt - 1; ++kt) {
        const int c = kt & 1;
        const char* bufA = ldsA + c * 16384;
        const char* bufB = ldsB + c * 49152;
        bf16x8 af[4][2], bq[2][2];
        // ---- phase 0: nj {0,1} ----
#pragma unroll
        for (int i = 0; i < 4; ++i) {
            af[i][0] = ldF(bufA, arow + (i << 4), 0);
            af[i][1] = ldF(bufA, arow + (i << 4), 1);
        }
#pragma unroll
        for (int j = 0; j < 2; ++j) {
            bq[j][0] = ldF(bufB, brow + (j << 6), 0);
            bq[j][1] = ldF(bufB, brow + (j << 6), 1);
        }
        issueA(c ^ 1, kt + 1); issueB(c ^ 1, kt + 1, 0); issueB(c ^ 1, kt + 1, 1);
        __builtin_amdgcn_s_barrier();
        asm volatile("s_waitcnt lgkmcnt(0)" ::: "memory");
        __builtin_amdgcn_sched_barrier(0);
        __builtin_amdgcn_s_setprio(1);
#pragma unroll
        for (int ks = 0; ks < 2; ++ks)
#pragma unroll
            for (int i = 0; i < 4; ++i)
#pragma unroll
                for (int j = 0; j < 2; ++j)
                    acc[i][j] = MFMA16(af[i][ks], bq[j][ks], acc[i][j]);
        __builtin_amdgcn_s_setprio(0);
        asm volatile("s_waitcnt vmcnt(8)" ::: "memory"); // B-b(kt) landed
        __builtin_amdgcn_s_barrier();
        // ---- phase 1: nj {2,3} ----
#pragma unroll
        for (int j = 0; j < 2; ++j) {
            bq[j][0] = ldF(bufB, brow + ((j + 2) << 6), 0);
            bq[j][1] = ldF(bufB, brow + ((j + 2) << 6), 1);
        }
        issueB(c ^ 1, kt + 1, 2);
        __builtin_amdgcn_s_barrier();
        asm volatile("s_waitcnt lgkmcnt(0)" ::: "memory");
        __builtin_amdgcn_sched_barrier(0);
        __builtin_amdgcn_s_setprio(1);
#pragma unroll
        for (int ks = 0; ks < 2; ++ks)
#pragma unroll
            for (int i = 0; i < 4; ++i)
#pragma unroll
                for (int j = 0; j < 2; ++j)
                    acc[i][j + 2] = MFMA16(af[i][ks], bq[j][ks], acc[i][j + 2]);
        __builtin_amdgcn_s_setprio(0);
        asm volatile("s_waitcnt vmcnt(8)" ::: "memory"); // B-c(kt) landed
        __builtin_amdgcn_s_barrier();
        // ---- phase 2: nj {4,5} ----
#pragma unroll
        for (int j = 0; j < 2; ++j) {
            bq[j][0] = ldF(bufB, brow + ((j + 4) << 6), 0);
            bq[j][1] = ldF(bufB, brow + ((j + 4) << 6), 1);
        }
        __builtin_amdgcn_s_barrier();
        asm volatile("s_waitcnt lgkmcnt(0)" ::: "memory");
        __builtin_amdgcn_sched_barrier(0);
        __builtin_amdgcn_s_setprio(1);
#pragma unroll
        for (int ks = 0; ks < 2; ++ks)
#pragma unroll
            for (int i = 0; i < 4; ++i)
#pragma unroll
                for (int j = 0; j < 2; ++j)
                    acc[i][j + 4] = MFMA16(af[i][ks], bq[j][ks], acc[i][j + 4]);
        __builtin_amdgcn_s_setprio(0);
        asm volatile("s_waitcnt vmcnt(4)" ::: "memory"); // A(kt+1), B-a(kt+1) landed
        __builtin_amdgcn_s_barrier();
    }

    { // ---- peeled last tile ----
        const int c = (nkt - 1) & 1;
        const char* bufA = ldsA + c * 16384;
        const char* bufB = ldsB + c * 49152;
        bf16x8 af[4][2], bq[2][2];
#pragma unroll
        for (int i = 0; i < 4; ++i) {
            af[i][0] = ldF(bufA, arow + (i << 4), 0);
            af[i][1] = ldF(bufA, arow + (i << 4), 1);
        }
#pragma unroll
        for (int j = 0; j < 2; ++j) {
            bq[j][0] = ldF(bufB, brow + (j << 6), 0);
            bq[j][1] = ldF(bufB, brow + (j << 6), 1);
        }
        __builtin_amdgcn_s_barrier();
        asm volatile("s_waitcnt lgkmcnt(0)" ::: "memory");
        __builtin_amdgcn_sched_barrier(0);
        __builtin_amdgcn_s_setprio(1);
#pragma unroll
        for (int ks = 0; ks < 2; ++ks)
#pragma unroll
            for (int i = 0; i < 4; ++i)
#pragma unroll
                for (int j = 0; j < 2; ++j)
                    acc[i][j] = MFMA16(af[i][ks], bq[j][ks], acc[i][j]);
        __builtin_amdgcn_s_setprio(0);
        asm volatile("s_waitcnt vmcnt(2)" ::: "memory");
        __builtin_amdgcn_s_barrier();
#pragma unroll
        for (int j = 0; j < 2; ++j) {
            bq[j][0] = ldF(bufB, brow + ((j + 2) << 6), 0);
            bq[j][1] = ldF(bufB, brow + ((j + 2) << 6), 1);
        }
        __builtin_amdgcn_s_barrier();
        asm volatile("s_waitcnt lgkmcnt(0)" ::: "memory");
        __builtin_amdgcn_sched_barrier(0);
        __builtin_amdgcn_s_setprio(1);
#pragma unroll
        for (int ks = 0; ks < 2; ++ks)
#pragma unroll
            for (int i = 0; i < 4; ++i)
#pragma unroll
                for (int j = 0; j < 2; ++j)
                    acc[i][j + 2] = MFMA16(af[i][ks], bq[j][ks], acc[i][j + 2]);
        __builtin_amdgcn_s_setprio(0);
        asm volatile("s_waitcnt vmcnt(0)" ::: "memory");
        __builtin_amdgcn_s_barrier();
#pragma unroll
        for (int j = 0; j < 2; ++j) {
            bq[j][0] = ldF(bufB, brow + ((j + 4) << 6), 0);
            bq[j][1] = ldF(bufB, brow + ((j + 4) << 6), 1);
        }
        __builtin_amdgcn_s_barrier();
        asm volatile("s_waitcnt lgkmcnt(0)" ::: "memory");
        __builtin_amdgcn_sched_barrier(0);
        __builtin_amdgcn_s_setprio(1);
#pragma unroll
        for (int ks = 0; ks < 2; ++ks)
#pragma unroll
            for (int i = 0; i < 4; ++i)
#pragma unroll
                for (int j = 0; j < 2; ++j)
                    acc[i][j + 4] = MFMA16(af[i][ks], bq[j][ks], acc[i][j + 4]);
        __builtin_amdgcn_s_setprio(0);
    }

    // ---- epilogue: rope + head split (Q/K); direct V^T write (V) ----
    const int d = (wn << 4) + lo16; // [0,64)
#pragma unroll
    for (int p = 0; p < 3; ++p) {
        const int gcb = col0 + (p << 7);
        const int seg = gcb >> 11;            // 0=q 1=k 2=v
        const int hb = (gcb >> 7) & 15;
        if (seg < 2) {
            bf16* dst0 = (seg == 0) ? Oq : Ok;
            const float qs = (seg == 0) ? ATTN_SCALE : 1.0f;
#pragma unroll
            for (int mi = 0; mi < 4; ++mi)
#pragma unroll
                for (int r = 0; r < 4; ++r) {
                    const int gm = row0 + (wm << 6) + (mi << 4) + (hi4 << 2) + r;
                    const int b = gm >> 11, t = gm & 2047;
                    const float2 csv = cs[t * 64 + d];
                    bf16* drow = dst0 + ((((size_t)b * Hn + hb) * Tsz + t) << 7);
                    const float vlo = acc[mi][2 * p][r];
                    const float vhi = acc[mi][2 * p + 1][r];
                    drow[d]      = (bf16)((vlo * csv.x - vhi * csv.y) * qs);
                    drow[d + 64] = (bf16)((vhi * csv.x + vlo * csv.y) * qs);
                }
        } else {
            // V^T [B,H,D,T]: r=0..3 are consecutive t -> one u32x2 (4 bf16) per d
#pragma unroll
            for (int mi = 0; mi < 4; ++mi) {
                const int t0 = row0 + (wm << 6) + (mi << 4) + (hi4 << 2);
                const int b = t0 >> 11, tt = t0 & 2047;
                bf16* vbase = Vt + (((size_t)b * Hn + hb) * Dh) * Tsz + tt;
                u32x2 wlo = {cvt_pk_bf16(acc[mi][2 * p][0], acc[mi][2 * p][1]),
                             cvt_pk_bf16(acc[mi][2 * p][2], acc[mi][2 * p][3])};
                u32x2 whi = {cvt_pk_bf16(acc[mi][2 * p + 1][0], acc[mi][2 * p + 1][1]),
                             cvt_pk_bf16(acc[mi][2 * p + 1][2], acc[mi][2 * p + 1][3])};
                *(u32x2*)(vbase + (size_t)d * Tsz)        = wlo;
                *(u32x2*)(vbase + (size_t)(d + 64) * Tsz) = whi;
            }
        }
    }
}

// =============== 128x256 output-projection GEMM, counted 2-phase (round-8/12) ===============
__global__ __launch_bounds__(512, 2)
void gemm256_proj(const bf16* __restrict__ A, const bf16* __restrict__ Bt,
                  float* __restrict__ Cf, int K) {
    __shared__ bf16 sA[2][128 * 64];
    __shared__ bf16 sB[2][256 * 64];
    const int tid = threadIdx.x, lane = tid & 63, wid = tid >> 6;
    const int wm = wid >> 2, wn = wid & 3;
    const int lo16 = lane & 15, hi4 = lane >> 4;
    const int N = 2048;

    const int cpx = gridDim.x >> 3;
    const int swz = (blockIdx.x & 7) * cpx + (blockIdx.x >> 3);
    const int by = swz & 31;   // M/128 = 32
    const int bx = swz >> 5;   // N/256 = 8
    const int row0 = by << 7, col0 = bx << 8;

    const int srow = tid >> 3;
    const int swzoff = (((tid & 7) ^ ((tid >> 3) & 7)) << 3);
    const bf16* srcA = A  + (size_t)(row0 + srow) * K + swzoff;
    const bf16* srcB = Bt + (size_t)(col0 + srow) * K + swzoff;
    const size_t K64 = (size_t)K * 64;
    char* const ldsA = (char*)&sA[0][0];
    char* const ldsB = (char*)&sB[0][0];
    const int wuo = wid << 10;

    auto issueA = [&](int c, int kt) {
        const bf16* s = srcA + (size_t)kt * 64;
        gld16(s,       ldsA + c * 16384 + 0    + wuo);
        gld16(s + K64, ldsA + c * 16384 + 8192 + wuo);
    };
    auto issueB = [&](int c, int kt, int u) { // B rows [128u, 128u+128)
        const bf16* s = srcB + (size_t)kt * 64 + (size_t)(2 * u) * K64;
        gld16(s,       ldsB + c * 32768 + u * 16384 + 0    + wuo);
        gld16(s + K64, ldsB + c * 32768 + u * 16384 + 8192 + wuo);
    };
    auto ldF = [&](const char* buf, int row, int ks) {
        return *(const bf16x8*)(buf + row * 128 + ((((ks << 2) + hi4) ^ (row & 7)) << 4));
    };

    const int arow = (wm << 6) + lo16;   // + mi*16
    const int brow = (wn << 4) + lo16;   // + nj*64, nj in [0,4)

    f32x4 acc[4][4] = {};
    const int nkt = K >> 6;

    issueA(0, 0); issueB(0, 0, 0); issueB(0, 0, 1);
    if (nkt > 1) { issueA(1, 1); issueB(1, 1, 0); }
    asm volatile("s_waitcnt vmcnt(4)" ::: "memory");
    __builtin_amdgcn_s_barrier();

    for (int kt = 0; kt < nkt; ++kt) {
        const int c = kt & 1;
        const char* bufA = ldsA + c * 16384;
        const char* bufB = ldsB + c * 32768;
        bf16x8 af[4][2], bq[2][2];
        // ---- phase 0: nj {0,1} (+ all A frags) ----
#pragma unroll
        for (int i = 0; i < 4; ++i) {
            af[i][0] = ldF(bufA, arow + (i << 4), 0);
            af[i][1] = ldF(bufA, arow + (i << 4), 1);
        }
#pragma unroll
        for (int j = 0; j < 2; ++j) {
            bq[j][0] = ldF(bufB, brow + (j << 6), 0);
            bq[j][1] = ldF(bufB, brow + (j << 6), 1);
        }
        if (kt + 1 < nkt) issueB(c ^ 1, kt + 1, 1);   // Bb(kt+1)
        __builtin_amdgcn_s_barrier();
        asm volatile("s_waitcnt lgkmcnt(0)" ::: "memory");
        __builtin_amdgcn_sched_barrier(0);
        __builtin_amdgcn_s_setprio(1);
#pragma unroll
        for (int ks = 0; ks < 2; ++ks)
#pragma unroll
            for (int i = 0; i < 4; ++i)
#pragma unroll
                for (int j = 0; j < 2; ++j)
                    acc[i][j] = MFMA16(af[i][ks], bq[j][ks], acc[i][j]);
        __builtin_amdgcn_s_setprio(0);
        if (kt + 1 < nkt) asm volatile("s_waitcnt vmcnt(6)" ::: "memory");
        else              asm volatile("s_waitcnt vmcnt(0)" ::: "memory");
        __builtin_amdgcn_s_barrier();
        // ---- phase 1: nj {2,3} ----
#pragma unroll
        for (int j = 0; j < 2; ++j) {
            bq[j][0] = ldF(bufB, brow + ((j + 2) << 6), 0);
            bq[j][1] = ldF(bufB, brow + ((j + 2) << 6), 1);
        }
        if (kt + 2 < nkt) { issueA(c, kt + 2); issueB(c, kt + 2, 0); }
        __builtin_amdgcn_s_barrier();
        asm volatile("s_waitcnt lgkmcnt(0)" ::: "memory");
        __builtin_amdgcn_sched_barrier(0);
        __builtin_amdgcn_s_setprio(1);
#pragma unroll
        for (int ks = 0; ks < 2; ++ks)
#pragma unroll
            for (int i = 0; i < 4; ++i)
#pragma unroll
                for (int j = 0; j < 2; ++j)
                    acc[i][j + 2] = MFMA16(af[i][ks], bq[j][ks], acc[i][j + 2]);
        __builtin_amdgcn_s_setprio(0);
        if (kt + 2 < nkt)      asm volatile("s_waitcnt vmcnt(6)" ::: "memory");
        else if (kt + 1 < nkt) asm volatile("s_waitcnt vmcnt(2)" ::: "memory");
        __builtin_amdgcn_s_barrier();
    }

    // ---- epilogue: plain f32 C write ----
#pragma unroll
    for (int mi = 0; mi < 4; ++mi)
#pragma unroll
        for (int r = 0; r < 4; ++r) {
            const int gm = row0 + (wm << 6) + (mi << 4) + (hi4 << 2) + r;
            float* crow = Cf + (size_t)gm * N + col0 + (wn << 4) + lo16;
#pragma unroll
            for (int nj = 0; nj < 4; ++nj)
                crow[nj << 6] = acc[mi][nj][r];
        }
}

// ---------------- flash attention (round-12 structure + XCD-pinned bh) ----------------
// xcd = i&7 owns bh {4*xcd..4*xcd+3} (4 MB KV = one XCD's L2); slot covers the
// r12 pairing: slot<8 -> t=15-slot (heavy), slot>=8 -> t=slot-8 (light).
// Per-block work, grid size (512), and 2 blocks/CU identical to round-12.
__device__ __forceinline__ void stage_tile(const bf16* __restrict__ Kb,
                                           const bf16* __restrict__ Vtb,
                                           bf16* sKc, bf16* sVc, int k0, int tid) {
#pragma unroll
    for (int c = 0; c < 4; ++c) {
        const int off = (c << 12) + (tid << 4);
        const int row = off >> 8, u = (off >> 4) & 15;
        gld16(Kb + (size_t)(k0 + row) * Dh + ((u ^ (row & 7)) << 3), (char*)sKc + off);
        const int dv = off >> 7, uv = (off >> 4) & 7;
        gld16(Vtb + (size_t)dv * Tsz + k0 + ((uv ^ (dv & 7)) << 3), (char*)sVc + off);
    }
}

__global__ __launch_bounds__(256, 2)
void attn_kernel(const bf16* __restrict__ Q, const bf16* __restrict__ K,
                 const bf16* __restrict__ Vt, bf16* __restrict__ Y) {
    __shared__ bf16 sK[2][64 * 128];
    __shared__ bf16 sV[2][128 * 64];
    const int tid = threadIdx.x, lane = tid & 63, wv = tid >> 6;
    const int lo32 = lane & 31, hl = lane >> 5;

    const int i = blockIdx.x;
    const int xcd = i & 7;
    const int j = i >> 3;                    // [0,64)
    const int bh = (xcd << 2) + (j & 3);     // XCD-pinned bh
    const int slot = j >> 2;                 // [0,16)
    const int t = (slot < 8) ? (15 - slot) : (slot - 8);
    const int b = bh >> 4, h = bh & 15;

    const int q0 = t << 7;
    const int q0w = q0 + (wv << 5);
    const int qg = q0w + lo32;

    const bf16* Kb  = K  + (size_t)bh * (Tsz * Dh);
    const bf16* Vtb = Vt + (size_t)bh * (Tsz * Dh);
    const bf16* Qp  = Q  + (size_t)bh * (Tsz * Dh) + (size_t)qg * Dh;

    bf16x8 qf[8];
#pragma unroll
    for (int kc = 0; kc < 8; ++kc)
        qf[kc] = *(const bf16x8*)(Qp + (kc << 4) + (hl << 3));

    float m = -1e30f, lsum = 0.f;
    f32x16 o[4] = {};

    const int nt_block = 2 * t + 2;
    const int nt_warp = ((q0w + 31) >> 6) + 1;

    stage_tile(Kb, Vtb, &sK[0][0], &sV[0][0], 0, tid);

    int cur = 0;
    for (int kt = 0; kt < nt_block; ++kt) {
        __syncthreads();
        if (kt + 1 < nt_block)
            stage_tile(Kb, Vtb, &sK[cur ^ 1][0], &sV[cur ^ 1][0], (kt + 1) << 6, tid);
        if (kt < nt_warp) {
            const int k0 = kt << 6;
            const bf16* kbuf = &sK[cur][0];
            const bf16* vbuf = &sV[cur][0];
            f32x16 s0 = {}, s1 = {};
            const int swk = lo32 & 7;
            __builtin_amdgcn_s_setprio(1);
#pragma unroll
            for (int kc = 0; kc < 8; ++kc) {
                bf16x8 kf0 = *(const bf16x8*)((const char*)kbuf + lo32 * 256 +
                              ((((kc << 1) + hl) ^ swk) << 4));
                s0 = MFMA32(kf0, qf[kc], s0);
                bf16x8 kf1 = *(const bf16x8*)((const char*)kbuf + (32 + lo32) * 256 +
                              ((((kc << 1) + hl) ^ swk) << 4));
                s1 = MFMA32(kf1, qf[kc], s1);
            }
            __builtin_amdgcn_s_setprio(0);

            const bool bnd = (k0 + 63 > q0w);
            if (bnd) {
#pragma unroll
                for (int r = 0; r < 16; ++r) {
                    const int kl = (r & 3) + ((r >> 2) << 3) + (hl << 2);
                    if (k0 + kl > qg)      s0[r] = -1e30f;
                    if (k0 + 32 + kl > qg) s1[r] = -1e30f;
                }
            }
            float pm = s0[0];
#pragma unroll
            for (int r = 1; r < 16; ++r) pm = fmaxf(pm, s0[r]);
#pragma unroll
            for (int r = 0; r < 16; ++r) pm = fmaxf(pm, s1[r]);
            pm = fmaxf(pm, __shfl_xor(pm, 32));

            if (__any(pm > m + 8.0f)) {
                const float mn = fmaxf(m, pm);
                const float sc = __expf(m - mn);
                m = mn;
                lsum *= sc;
#pragma unroll
                for (int db = 0; db < 4; ++db)
#pragma unroll
                    for (int r = 0; r < 16; ++r) o[db][r] *= sc;
            }
            float rs = 0.f;
            if (bnd) {
#pragma unroll
                for (int r = 0; r < 16; ++r) {
                    float e0 = (s0[r] > -1e29f) ? __expf(s0[r] - m) : 0.f;
                    float e1 = (s1[r] > -1e29f) ? __expf(s1[r] - m) : 0.f;
                    s0[r] = e0; s1[r] = e1; rs += e0 + e1;
                }
            } else {
#pragma unroll
                for (int r = 0; r < 16; ++r) {
                    float e0 = __expf(s0[r] - m);
                    float e1 = __expf(s1[r] - m);
                    s0[r] = e0; s1[r] = e1; rs += e0 + e1;
                }
            }
            rs += __shfl_xor(rs, 32);
            lsum += rs;

            bf16x8 pb0 = make_pfrag(s0[0], s0[1], s0[2],  s0[3],  s0[4],  s0[5],  s0[6],  s0[7]);
            bf16x8 pb1 = make_pfrag(s0[8], s0[9], s0[10], s0[11], s0[12], s0[13], s0[14], s0[15]);
            bf16x8 pb2 = make_pfrag(s1[0], s1[1], s1[2],  s1[3],  s1[4],  s1[5],  s1[6],  s1[7]);
            bf16x8 pb3 = make_pfrag(s1[8], s1[9], s1[10], s1[11], s1[12], s1[13], s1[14], s1[15]);

            __builtin_amdgcn_s_setprio(1);
#pragma unroll
            for (int db = 0; db < 4; ++db) {
                const int rd = (db << 5) + lo32;
                const char* vrow = (const char*)vbuf + rd * 128;
                const int sw = rd & 7;
                bf16x8 v0 = *(const bf16x8*)(vrow + (((0 + hl) ^ sw) << 4));
                o[db] = MFMA32(v0, pb0, o[db]);
                bf16x8 v1 = *(const bf16x8*)(vrow + (((2 + hl) ^ sw) << 4));
                o[db] = MFMA32(v1, pb1, o[db]);
                bf16x8 v2 = *(const bf16x8*)(vrow + (((4 + hl) ^ sw) << 4));
                o[db] = MFMA32(v2, pb2, o[db]);
                bf16x8 v3 = *(const bf16x8*)(vrow + (((6 + hl) ^ sw) << 4));
                o[db] = MFMA32(v3, pb3, o[db]);
            }
            __builtin_amdgcn_s_setprio(0);
        }
        cur ^= 1;
    }

    const float inv = 1.0f / lsum;
    const size_t rowoff = ((size_t)b * Tsz + qg) * (size_t)Csz + (size_t)h * 128;
#pragma unroll
    for (int db = 0; db < 4; ++db)
#pragma unroll
        for (int gg = 0; gg < 4; ++gg) {
            unsigned w0 = cvt_pk_bf16(o[db][4 * gg + 0] * inv, o[db][4 * gg + 1] * inv);
            unsigned w1 = cvt_pk_bf16(o[db][4 * gg + 2] * inv, o[db][4 * gg + 3] * inv);
            u32x2 w = {w0, w1};
            *(u32x2*)(Y + rowoff + (db << 5) + (gg << 3) + (hl << 2)) = w;
        }
}

extern "C" void kernel_launch(void* const* d_in, const int* in_sizes, int n_in,
                              void* d_out, int out_size, void* d_ws, size_t ws_size,
                              hipStream_t stream) {
    const float* x      = (const float*)d_in[0];
    const float* w_attn = (const float*)d_in[1];
    const float* w_proj = (const float*)d_in[2];
    float* out = (float*)d_out;

    char* ws = (char*)d_ws;
    bf16* Xb  = (bf16*)(ws);                 // 4096x2048           16 MB
    bf16* Wat = (bf16*)(ws + 16777216);      // 6144x2048 (W^T)     24 MB
    bf16* Wpt = (bf16*)(ws + 41943040);      // 2048x2048 (W^T)      8 MB
    bf16* Qr  = (bf16*)(ws + 50331648);      // [B,H,T,D] (scaled)  16 MB
    bf16* Kr  = (bf16*)(ws + 67108864);      // [B,H,T,D]           16 MB
    bf16* Vt  = (bf16*)(ws + 100663296);     // [B,H,D,T]           16 MB
    bf16* Yb  = (bf16*)(ws + 117440512);     // [B,T,C]             16 MB
    float2* cs = (float2*)(ws + 134217728);  // [T,64]               1 MB

    prep_kernel<<<4608, 256, 0, stream>>>(x, Xb, cs, (Bsz * Tsz * Csz) / 8);
    transpose_cast_kernel<float><<<dim3(96, 32, 1), dim3(64, 4), 0, stream>>>(w_attn, Wat, 2048, 6144);
    transpose_cast_kernel<float><<<dim3(32, 32, 1), dim3(64, 4), 0, stream>>>(w_proj, Wpt, 2048, 2048);

    gemm384_qkv<<<512, 512, 0, stream>>>(Xb, Wat, Qr, Kr, Vt, cs, 2048);

    attn_kernel<<<dim3(512), 256, 0, stream>>>(Qr, Kr, Vt, Yb);

    gemm256_proj<<<256, 512, 0, stream>>>(Yb, Wpt, out, 2048);
}

// Round 16
// 229.606 us; speedup vs baseline: 1.0994x; 1.0199x over previous
//
#include <hip/hip_runtime.h>
#include <hip/hip_bf16.h>
#include <math.h>

typedef __bf16 bf16;
typedef __bf16 bf16x8 __attribute__((ext_vector_type(8)));
typedef __bf16 bf16x4v __attribute__((ext_vector_type(4)));
typedef float f32x4 __attribute__((ext_vector_type(4)));
typedef float f32x16 __attribute__((ext_vector_type(16)));
typedef unsigned int u32x2 __attribute__((ext_vector_type(2)));
typedef unsigned int u32x4 __attribute__((ext_vector_type(4)));

#define MFMA16(a, b, c) __builtin_amdgcn_mfma_f32_16x16x32_bf16((a), (b), (c), 0, 0, 0)
#define MFMA32(a, b, c) __builtin_amdgcn_mfma_f32_32x32x16_bf16((a), (b), (c), 0, 0, 0)

static constexpr int Bsz = 2, Tsz = 2048, Csz = 2048, Hn = 16, Dh = 128;
static constexpr float ATTN_SCALE = 0.08838834764831845f; // 1/sqrt(128)

__device__ __forceinline__ void gld16(const void* src, void* dst) {
    __builtin_amdgcn_global_load_lds((__attribute__((address_space(1))) void*)src,
                                     (__attribute__((address_space(3))) void*)dst,
                                     16, 0, 0);
}

__device__ __forceinline__ unsigned cvt_pk_bf16(float lo, float hi) {
    unsigned r;
    asm("v_cvt_pk_bf16_f32 %0, %1, %2" : "=v"(r) : "v"(lo), "v"(hi));
    return r;
}

__device__ __forceinline__ bf16x8 make_pfrag(float p0, float p1, float p2, float p3,
                                             float p4, float p5, float p6, float p7) {
    unsigned a0 = cvt_pk_bf16(p0, p1), a1 = cvt_pk_bf16(p2, p3);
    unsigned b0 = cvt_pk_bf16(p4, p5), b1 = cvt_pk_bf16(p6, p7);
    asm volatile("v_permlane32_swap_b32 %0, %1" : "+v"(a0), "+v"(b0));
    asm volatile("v_permlane32_swap_b32 %0, %1" : "+v"(a1), "+v"(b1));
    u32x4 w = {a0, a1, b0, b1};
    return __builtin_bit_cast(bf16x8, w);
}

// ======== fused prep: x cast + rope table + both weight transposes (1 launch) ========
// blocks [0,4096): x f32->bf16 (8/thread)
// blocks [4096,4608): cos/sin table
// blocks [4608,7680): w_attn transpose-cast (96x32 tiles of 64x64)
// blocks [7680,8704): w_proj transpose-cast (32x32 tiles)
__global__ __launch_bounds__(256)
void prep_all_kernel(const float* __restrict__ x, bf16* __restrict__ xb,
                     float2* __restrict__ cs,
                     const float* __restrict__ w_attn, bf16* __restrict__ wat,
                     const float* __restrict__ w_proj, bf16* __restrict__ wpt) {
    __shared__ float tile[64][65];
    const int bid = blockIdx.x, tid = threadIdx.x;
    if (bid < 4096) {
        const int i = bid * 256 + tid;
        const float4* x4 = (const float4*)x;
        float4 a = x4[2 * i], b = x4[2 * i + 1];
        bf16x8 v;
        v[0] = (bf16)a.x; v[1] = (bf16)a.y; v[2] = (bf16)a.z; v[3] = (bf16)a.w;
        v[4] = (bf16)b.x; v[5] = (bf16)b.y; v[6] = (bf16)b.z; v[7] = (bf16)b.w;
        ((bf16x8*)xb)[i] = v;
        return;
    }
    if (bid < 4608) {
        const int idx = (bid - 4096) * 256 + tid; // 2048*64
        const int t = idx >> 6, i = idx & 63;
        float theta = 1.0f / powf(10000.0f, (float)(2 * i) / 128.0f);
        float ang = (float)t * theta;
        cs[idx] = make_float2(cosf(ang), sinf(ang));
        return;
    }
    // transpose-cast branches (block-uniform)
    const float* in;
    bf16* out;
    int R, Cc, bx, by;
    if (bid < 7680) {
        const int f = bid - 4608;
        in = w_attn; out = wat; R = 2048; Cc = 6144;
        bx = f % 96; by = f / 96;
    } else {
        const int f = bid - 7680;
        in = w_proj; out = wpt; R = 2048; Cc = 2048;
        bx = f & 31; by = f >> 5;
    }
    const int tx = tid & 63, ty = tid >> 6;
    const int c0 = bx * 64, r0 = by * 64;
#pragma unroll
    for (int j = 0; j < 16; ++j) {
        int rr = ty + j * 4;
        tile[rr][tx] = in[(size_t)(r0 + rr) * Cc + c0 + tx];
    }
    __syncthreads();
    const int q = (tx & 15) << 2;  // row-quad base
    const int cg = tx >> 4;        // col-group [0,4)
#pragma unroll
    for (int j = 0; j < 4; ++j) {
        const int cc = j * 16 + cg * 4 + ty;
        bf16x4v v;
        v[0] = (bf16)tile[q + 0][cc];
        v[1] = (bf16)tile[q + 1][cc];
        v[2] = (bf16)tile[q + 2][cc];
        v[3] = (bf16)tile[q + 3][cc];
        *(bf16x4v*)(out + (size_t)(c0 + cc) * R + r0 + q) = v;
    }
}

// =============== 128x384 GEMM, deep counted-vmcnt pipeline (round-5/8 best) ===============
// Fused epilogue: rope+head-split for Q/K; V written DIRECTLY as V^T [B,H,D,T].
__global__ __launch_bounds__(512, 2)
void gemm384_qkv(const bf16* __restrict__ A, const bf16* __restrict__ Bt,
                 bf16* __restrict__ Oq, bf16* __restrict__ Ok, bf16* __restrict__ Vt,
                 const float2* __restrict__ cs, int K) {
    __shared__ bf16 sA[2][128 * 64];
    __shared__ bf16 sB[2][384 * 64];
    const int tid = threadIdx.x, lane = tid & 63, wid = tid >> 6;
    const int wm = wid >> 2, wn = wid & 3;
    const int lo16 = lane & 15, hi4 = lane >> 4;

    const int cpx = gridDim.x >> 3;
    const int swz = (blockIdx.x & 7) * cpx + (blockIdx.x >> 3);
    const int by = swz & 31;   // M/128 = 32
    const int bx = swz >> 5;   // N/384 = 16
    const int row0 = by << 7, col0 = bx * 384;

    const int srow = tid >> 3;                                   // [0,64)
    const int swzoff = (((tid & 7) ^ ((tid >> 3) & 7)) << 3);    // elements
    const bf16* srcA = A  + (size_t)(row0 + srow) * K + swzoff;
    const bf16* srcB = Bt + (size_t)(col0 + srow) * K + swzoff;
    const size_t K64 = (size_t)K * 64;
    char* const ldsA = (char*)&sA[0][0];
    char* const ldsB = (char*)&sB[0][0];
    const int wuo = wid << 10;

    auto issueA = [&](int c, int kt) {   // A tile 128x64 = 16KB
        const bf16* s = srcA + (size_t)kt * 64;
        gld16(s,       ldsA + c * 16384 + 0    + wuo);
        gld16(s + K64, ldsA + c * 16384 + 8192 + wuo);
    };
    auto issueB = [&](int c, int kt, int u) { // B rows [128u, 128u+128) = 16KB
        const bf16* s = srcB + (size_t)kt * 64 + (size_t)(2 * u) * K64;
        gld16(s,       ldsB + c * 49152 + u * 16384 + 0    + wuo);
        gld16(s + K64, ldsB + c * 49152 + u * 16384 + 8192 + wuo);
    };
    auto ldF = [&](const char* buf, int row, int ks) {
        return *(const bf16x8*)(buf + row * 128 + ((((ks << 2) + hi4) ^ (row & 7)) << 4));
    };

    const int arow = (wm << 6) + lo16;   // + mi*16, mi in [0,4)
    const int brow = (wn << 4) + lo16;   // + nj*64, nj in [0,6)

    f32x4 acc[4][6] = {};
    const int nkt = K >> 6;

    issueA(0, 0); issueB(0, 0, 0); issueB(0, 0, 1); issueB(0, 0, 2);
    asm volatile("s_waitcnt vmcnt(4)" ::: "memory");
    __builtin_amdgcn_s_barrier();

    for (int kt = 0; kt < nkt - 1; ++kt) {
        const int c = kt & 1;
        const char* bufA = ldsA + c * 16384;
        const char* bufB = ldsB + c * 49152;
        bf16x8 af[4][2], bq[2][2];
        // ---- phase 0: nj {0,1} ----
#pragma unroll
        for (int i = 0; i < 4; ++i) {
            af[i][0] = ldF(bufA, arow + (i << 4), 0);
            af[i][1] = ldF(bufA, arow + (i << 4), 1);
        }
#pragma unroll
        for (int j = 0; j < 2; ++j) {
            bq[j][0] = ldF(bufB, brow + (j << 6), 0);
            bq[j][1] = ldF(bufB, brow + (j << 6), 1);
        }
        issueA(c ^ 1, kt + 1); issueB(c ^ 1, kt + 1, 0); issueB(c ^ 1, kt + 1, 1);
        __builtin_amdgcn_s_barrier();
        asm volatile("s_waitcnt lgkmcnt(0)" ::: "memory");
        __builtin_amdgcn_sched_barrier(0);
        __builtin_amdgcn_s_setprio(1);
#pragma unroll
        for (int ks = 0; ks < 2; ++ks)
#pragma unroll
            for (int i = 0; i < 4; ++i)
#pragma unroll
                for (int j = 0; j < 2; ++j)
                    acc[i][j] = MFMA16(af[i][ks], bq[j][ks], acc[i][j]);
        __builtin_amdgcn_s_setprio(0);
        asm volatile("s_waitcnt vmcnt(8)" ::: "memory"); // B-b(kt) landed
        __builtin_amdgcn_s_barrier();
        // ---- phase 1: nj {2,3} ----
#pragma unroll
        for (int j = 0; j < 2; ++j) {
            bq[j][0] = ldF(bufB, brow + ((j + 2) << 6), 0);
            bq[j][1] = ldF(bufB, brow + ((j + 2) << 6), 1);
        }
        issueB(c ^ 1, kt + 1, 2);
        __builtin_amdgcn_s_barrier();
        asm volatile("s_waitcnt lgkmcnt(0)" ::: "memory");
        __builtin_amdgcn_sched_barrier(0);
        __builtin_amdgcn_s_setprio(1);
#pragma unroll
        for (int ks = 0; ks < 2; ++ks)
#pragma unroll
            for (int i = 0; i < 4; ++i)
#pragma unroll
                for (int j = 0; j < 2; ++j)
                    acc[i][j + 2] = MFMA16(af[i][ks], bq[j][ks], acc[i][j + 2]);
        __builtin_amdgcn_s_setprio(0);
        asm volatile("s_waitcnt vmcnt(8)" ::: "memory"); // B-c(kt) landed
        __builtin_amdgcn_s_barrier();
        // ---- phase 2: nj {4,5} ----
#pragma unroll
        for (int j = 0; j < 2; ++j) {
            bq[j][0] = ldF(bufB, brow + ((j + 4) << 6), 0);
            bq[j][1] = ldF(bufB, brow + ((j + 4) << 6), 1);
        }
        __builtin_amdgcn_s_barrier();
        asm volatile("s_waitcnt lgkmcnt(0)" ::: "memory");
        __builtin_amdgcn_sched_barrier(0);
        __builtin_amdgcn_s_setprio(1);
#pragma unroll
        for (int ks = 0; ks < 2; ++ks)
#pragma unroll
            for (int i = 0; i < 4; ++i)
#pragma unroll
                for (int j = 0; j < 2; ++j)
                    acc[i][j + 4] = MFMA16(af[i][ks], bq[j][ks], acc[i][j + 4]);
        __builtin_amdgcn_s_setprio(0);
        asm volatile("s_waitcnt vmcnt(4)" ::: "memory"); // A(kt+1), B-a(kt+1) landed
        __builtin_amdgcn_s_barrier();
    }

    { // ---- peeled last tile ----
        const int c = (nkt - 1) & 1;
        const char* bufA = ldsA + c * 16384;
        const char* bufB = ldsB + c * 49152;
        bf16x8 af[4][2], bq[2][2];
#pragma unroll
        for (int i = 0; i < 4; ++i) {
            af[i][0] = ldF(bufA, arow + (i << 4), 0);
            af[i][1] = ldF(bufA, arow + (i << 4), 1);
        }
#pragma unroll
        for (int j = 0; j < 2; ++j) {
            bq[j][0] = ldF(bufB, brow + (j << 6), 0);
            bq[j][1] = ldF(bufB, brow + (j << 6), 1);
        }
        __builtin_amdgcn_s_barrier();
        asm volatile("s_waitcnt lgkmcnt(0)" ::: "memory");
        __builtin_amdgcn_sched_barrier(0);
        __builtin_amdgcn_s_setprio(1);
#pragma unroll
        for (int ks = 0; ks < 2; ++ks)
#pragma unroll
            for (int i = 0; i < 4; ++i)
#pragma unroll
                for (int j = 0; j < 2; ++j)
                    acc[i][j] = MFMA16(af[i][ks], bq[j][ks], acc[i][j]);
        __builtin_amdgcn_s_setprio(0);
        asm volatile("s_waitcnt vmcnt(2)" ::: "memory");
        __builtin_amdgcn_s_barrier();
#pragma unroll
        for (int j = 0; j < 2; ++j) {
            bq[j][0] = ldF(bufB, brow + ((j + 2) << 6), 0);
            bq[j][1] = ldF(bufB, brow + ((j + 2) << 6), 1);
        }
        __builtin_amdgcn_s_barrier();
        asm volatile("s_waitcnt lgkmcnt(0)" ::: "memory");
        __builtin_amdgcn_sched_barrier(0);
        __builtin_amdgcn_s_setprio(1);
#pragma unroll
        for (int ks = 0; ks < 2; ++ks)
#pragma unroll
            for (int i = 0; i < 4; ++i)
#pragma unroll
                for (int j = 0; j < 2; ++j)
                    acc[i][j + 2] = MFMA16(af[i][ks], bq[j][ks], acc[i][j + 2]);
        __builtin_amdgcn_s_setprio(0);
        asm volatile("s_waitcnt vmcnt(0)" ::: "memory");
        __builtin_amdgcn_s_barrier();
#pragma unroll
        for (int j = 0; j < 2; ++j) {
            bq[j][0] = ldF(bufB, brow + ((j + 4) << 6), 0);
            bq[j][1] = ldF(bufB, brow + ((j + 4) << 6), 1);
        }
        __builtin_amdgcn_s_barrier();
        asm volatile("s_waitcnt lgkmcnt(0)" ::: "memory");
        __builtin_amdgcn_sched_barrier(0);
        __builtin_amdgcn_s_setprio(1);
#pragma unroll
        for (int ks = 0; ks < 2; ++ks)
#pragma unroll
            for (int i = 0; i < 4; ++i)
#pragma unroll
                for (int j = 0; j < 2; ++j)
                    acc[i][j + 4] = MFMA16(af[i][ks], bq[j][ks], acc[i][j + 4]);
        __builtin_amdgcn_s_setprio(0);
    }

    // ---- epilogue: rope + head split (Q/K); direct V^T write (V) ----
    const int d = (wn << 4) + lo16; // [0,64)
#pragma unroll
    for (int p = 0; p < 3; ++p) {
        const int gcb = col0 + (p << 7);
        const int seg = gcb >> 11;            // 0=q 1=k 2=v
        const int hb = (gcb >> 7) & 15;
        if (seg < 2) {
            bf16* dst0 = (seg == 0) ? Oq : Ok;
            const float qs = (seg == 0) ? ATTN_SCALE : 1.0f;
#pragma unroll
            for (int mi = 0; mi < 4; ++mi)
#pragma unroll
                for (int r = 0; r < 4; ++r) {
                    const int gm = row0 + (wm << 6) + (mi << 4) + (hi4 << 2) + r;
                    const int b = gm >> 11, t = gm & 2047;
                    const float2 csv = cs[t * 64 + d];
                    bf16* drow = dst0 + ((((size_t)b * Hn + hb) * Tsz + t) << 7);
                    const float vlo = acc[mi][2 * p][r];
                    const float vhi = acc[mi][2 * p + 1][r];
                    drow[d]      = (bf16)((vlo * csv.x - vhi * csv.y) * qs);
                    drow[d + 64] = (bf16)((vhi * csv.x + vlo * csv.y) * qs);
                }
        } else {
            // V^T [B,H,D,T]: r=0..3 are consecutive t -> one u32x2 (4 bf16) per d
#pragma unroll
            for (int mi = 0; mi < 4; ++mi) {
                const int t0 = row0 + (wm << 6) + (mi << 4) + (hi4 << 2);
                const int b = t0 >> 11, tt = t0 & 2047;
                bf16* vbase = Vt + (((size_t)b * Hn + hb) * Dh) * Tsz + tt;
                u32x2 wlo = {cvt_pk_bf16(acc[mi][2 * p][0], acc[mi][2 * p][1]),
                             cvt_pk_bf16(acc[mi][2 * p][2], acc[mi][2 * p][3])};
                u32x2 whi = {cvt_pk_bf16(acc[mi][2 * p + 1][0], acc[mi][2 * p + 1][1]),
                             cvt_pk_bf16(acc[mi][2 * p + 1][2], acc[mi][2 * p + 1][3])};
                *(u32x2*)(vbase + (size_t)d * Tsz)        = wlo;
                *(u32x2*)(vbase + (size_t)(d + 64) * Tsz) = whi;
            }
        }
    }
}

// =============== 128x256 output-projection GEMM, counted 2-phase (round-8/12) ===============
__global__ __launch_bounds__(512, 2)
void gemm256_proj(const bf16* __restrict__ A, const bf16* __restrict__ Bt,
                  float* __restrict__ Cf, int K) {
    __shared__ bf16 sA[2][128 * 64];
    __shared__ bf16 sB[2][256 * 64];
    const int tid = threadIdx.x, lane = tid & 63, wid = tid >> 6;
    const int wm = wid >> 2, wn = wid & 3;
    const int lo16 = lane & 15, hi4 = lane >> 4;
    const int N = 2048;

    const int cpx = gridDim.x >> 3;
    const int swz = (blockIdx.x & 7) * cpx + (blockIdx.x >> 3);
    const int by = swz & 31;   // M/128 = 32
    const int bx = swz >> 5;   // N/256 = 8
    const int row0 = by << 7, col0 = bx << 8;

    const int srow = tid >> 3;
    const int swzoff = (((tid & 7) ^ ((tid >> 3) & 7)) << 3);
    const bf16* srcA = A  + (size_t)(row0 + srow) * K + swzoff;
    const bf16* srcB = Bt + (size_t)(col0 + srow) * K + swzoff;
    const size_t K64 = (size_t)K * 64;
    char* const ldsA = (char*)&sA[0][0];
    char* const ldsB = (char*)&sB[0][0];
    const int wuo = wid << 10;

    auto issueA = [&](int c, int kt) {
        const bf16* s = srcA + (size_t)kt * 64;
        gld16(s,       ldsA + c * 16384 + 0    + wuo);
        gld16(s + K64, ldsA + c * 16384 + 8192 + wuo);
    };
    auto issueB = [&](int c, int kt, int u) { // B rows [128u, 128u+128)
        const bf16* s = srcB + (size_t)kt * 64 + (size_t)(2 * u) * K64;
        gld16(s,       ldsB + c * 32768 + u * 16384 + 0    + wuo);
        gld16(s + K64, ldsB + c * 32768 + u * 16384 + 8192 + wuo);
    };
    auto ldF = [&](const char* buf, int row, int ks) {
        return *(const bf16x8*)(buf + row * 128 + ((((ks << 2) + hi4) ^ (row & 7)) << 4));
    };

    const int arow = (wm << 6) + lo16;   // + mi*16
    const int brow = (wn << 4) + lo16;   // + nj*64, nj in [0,4)

    f32x4 acc[4][4] = {};
    const int nkt = K >> 6;

    issueA(0, 0); issueB(0, 0, 0); issueB(0, 0, 1);
    if (nkt > 1) { issueA(1, 1); issueB(1, 1, 0); }
    asm volatile("s_waitcnt vmcnt(4)" ::: "memory");
    __builtin_amdgcn_s_barrier();

    for (int kt = 0; kt < nkt; ++kt) {
        const int c = kt & 1;
        const char* bufA = ldsA + c * 16384;
        const char* bufB = ldsB + c * 32768;
        bf16x8 af[4][2], bq[2][2];
        // ---- phase 0: nj {0,1} (+ all A frags) ----
#pragma unroll
        for (int i = 0; i < 4; ++i) {
            af[i][0] = ldF(bufA, arow + (i << 4), 0);
            af[i][1] = ldF(bufA, arow + (i << 4), 1);
        }
#pragma unroll
        for (int j = 0; j < 2; ++j) {
            bq[j][0] = ldF(bufB, brow + (j << 6), 0);
            bq[j][1] = ldF(bufB, brow + (j << 6), 1);
        }
        if (kt + 1 < nkt) issueB(c ^ 1, kt + 1, 1);   // Bb(kt+1)
        __builtin_amdgcn_s_barrier();
        asm volatile("s_waitcnt lgkmcnt(0)" ::: "memory");
        __builtin_amdgcn_sched_barrier(0);
        __builtin_amdgcn_s_setprio(1);
#pragma unroll
        for (int ks = 0; ks < 2; ++ks)
#pragma unroll
            for (int i = 0; i < 4; ++i)
#pragma unroll
                for (int j = 0; j < 2; ++j)
                    acc[i][j] = MFMA16(af[i][ks], bq[j][ks], acc[i][j]);
        __builtin_amdgcn_s_setprio(0);
        if (kt + 1 < nkt) asm volatile("s_waitcnt vmcnt(6)" ::: "memory");
        else              asm volatile("s_waitcnt vmcnt(0)" ::: "memory");
        __builtin_amdgcn_s_barrier();
        // ---- phase 1: nj {2,3} ----
#pragma unroll
        for (int j = 0; j < 2; ++j) {
            bq[j][0] = ldF(bufB, brow + ((j + 2) << 6), 0);
            bq[j][1] = ldF(bufB, brow + ((j + 2) << 6), 1);
        }
        if (kt + 2 < nkt) { issueA(c, kt + 2); issueB(c, kt + 2, 0); }
        __builtin_amdgcn_s_barrier();
        asm volatile("s_waitcnt lgkmcnt(0)" ::: "memory");
        __builtin_amdgcn_sched_barrier(0);
        __builtin_amdgcn_s_setprio(1);
#pragma unroll
        for (int ks = 0; ks < 2; ++ks)
#pragma unroll
            for (int i = 0; i < 4; ++i)
#pragma unroll
                for (int j = 0; j < 2; ++j)
                    acc[i][j + 2] = MFMA16(af[i][ks], bq[j][ks], acc[i][j + 2]);
        __builtin_amdgcn_s_setprio(0);
        if (kt + 2 < nkt)      asm volatile("s_waitcnt vmcnt(6)" ::: "memory");
        else if (kt + 1 < nkt) asm volatile("s_waitcnt vmcnt(2)" ::: "memory");
        __builtin_amdgcn_s_barrier();
    }

    // ---- epilogue: plain f32 C write ----
#pragma unroll
    for (int mi = 0; mi < 4; ++mi)
#pragma unroll
        for (int r = 0; r < 4; ++r) {
            const int gm = row0 + (wm << 6) + (mi << 4) + (hi4 << 2) + r;
            float* crow = Cf + (size_t)gm * N + col0 + (wn << 4) + lo16;
#pragma unroll
            for (int nj = 0; nj < 4; ++nj)
                crow[nj << 6] = acc[mi][nj][r];
        }
}

// ---------------- flash attention (round-12 structure + XCD-pinned bh, r15 best) ----------------
__device__ __forceinline__ void stage_tile(const bf16* __restrict__ Kb,
                                           const bf16* __restrict__ Vtb,
                                           bf16* sKc, bf16* sVc, int k0, int tid) {
#pragma unroll
    for (int c = 0; c < 4; ++c) {
        const int off = (c << 12) + (tid << 4);
        const int row = off >> 8, u = (off >> 4) & 15;
        gld16(Kb + (size_t)(k0 + row) * Dh + ((u ^ (row & 7)) << 3), (char*)sKc + off);
        const int dv = off >> 7, uv = (off >> 4) & 7;
        gld16(Vtb + (size_t)dv * Tsz + k0 + ((uv ^ (dv & 7)) << 3), (char*)sVc + off);
    }
}

__global__ __launch_bounds__(256, 2)
void attn_kernel(const bf16* __restrict__ Q, const bf16* __restrict__ K,
                 const bf16* __restrict__ Vt, bf16* __restrict__ Y) {
    __shared__ bf16 sK[2][64 * 128];
    __shared__ bf16 sV[2][128 * 64];
    const int tid = threadIdx.x, lane = tid & 63, wv = tid >> 6;
    const int lo32 = lane & 31, hl = lane >> 5;

    const int i = blockIdx.x;
    const int xcd = i & 7;
    const int j = i >> 3;                    // [0,64)
    const int bh = (xcd << 2) + (j & 3);     // XCD-pinned bh
    const int slot = j >> 2;                 // [0,16)
    const int t = (slot < 8) ? (15 - slot) : (slot - 8);
    const int b = bh >> 4, h = bh & 15;

    const int q0 = t << 7;
    const int q0w = q0 + (wv << 5);
    const int qg = q0w + lo32;

    const bf16* Kb  = K  + (size_t)bh * (Tsz * Dh);
    const bf16* Vtb = Vt + (size_t)bh * (Tsz * Dh);
    const bf16* Qp  = Q  + (size_t)bh * (Tsz * Dh) + (size_t)qg * Dh;

    bf16x8 qf[8];
#pragma unroll
    for (int kc = 0; kc < 8; ++kc)
        qf[kc] = *(const bf16x8*)(Qp + (kc << 4) + (hl << 3));

    float m = -1e30f, lsum = 0.f;
    f32x16 o[4] = {};

    const int nt_block = 2 * t + 2;
    const int nt_warp = ((q0w + 31) >> 6) + 1;

    stage_tile(Kb, Vtb, &sK[0][0], &sV[0][0], 0, tid);

    int cur = 0;
    for (int kt = 0; kt < nt_block; ++kt) {
        __syncthreads();
        if (kt + 1 < nt_block)
            stage_tile(Kb, Vtb, &sK[cur ^ 1][0], &sV[cur ^ 1][0], (kt + 1) << 6, tid);
        if (kt < nt_warp) {
            const int k0 = kt << 6;
            const bf16* kbuf = &sK[cur][0];
            const bf16* vbuf = &sV[cur][0];
            f32x16 s0 = {}, s1 = {};
            const int swk = lo32 & 7;
            __builtin_amdgcn_s_setprio(1);
#pragma unroll
            for (int kc = 0; kc < 8; ++kc) {
                bf16x8 kf0 = *(const bf16x8*)((const char*)kbuf + lo32 * 256 +
                              ((((kc << 1) + hl) ^ swk) << 4));
                s0 = MFMA32(kf0, qf[kc], s0);
                bf16x8 kf1 = *(const bf16x8*)((const char*)kbuf + (32 + lo32) * 256 +
                              ((((kc << 1) + hl) ^ swk) << 4));
                s1 = MFMA32(kf1, qf[kc], s1);
            }
            __builtin_amdgcn_s_setprio(0);

            const bool bnd = (k0 + 63 > q0w);
            if (bnd) {
#pragma unroll
                for (int r = 0; r < 16; ++r) {
                    const int kl = (r & 3) + ((r >> 2) << 3) + (hl << 2);
                    if (k0 + kl > qg)      s0[r] = -1e30f;
                    if (k0 + 32 + kl > qg) s1[r] = -1e30f;
                }
            }
            float pm = s0[0];
#pragma unroll
            for (int r = 1; r < 16; ++r) pm = fmaxf(pm, s0[r]);
#pragma unroll
            for (int r = 0; r < 16; ++r) pm = fmaxf(pm, s1[r]);
            pm = fmaxf(pm, __shfl_xor(pm, 32));

            if (__any(pm > m + 8.0f)) {
                const float mn = fmaxf(m, pm);
                const float sc = __expf(m - mn);
                m = mn;
                lsum *= sc;
#pragma unroll
                for (int db = 0; db < 4; ++db)
#pragma unroll
                    for (int r = 0; r < 16; ++r) o[db][r] *= sc;
            }
            float rs = 0.f;
            if (bnd) {
#pragma unroll
                for (int r = 0; r < 16; ++r) {
                    float e0 = (s0[r] > -1e29f) ? __expf(s0[r] - m) : 0.f;
                    float e1 = (s1[r] > -1e29f) ? __expf(s1[r] - m) : 0.f;
                    s0[r] = e0; s1[r] = e1; rs += e0 + e1;
                }
            } else {
#pragma unroll
                for (int r = 0; r < 16; ++r) {
                    float e0 = __expf(s0[r] - m);
                    float e1 = __expf(s1[r] - m);
                    s0[r] = e0; s1[r] = e1; rs += e0 + e1;
                }
            }
            rs += __shfl_xor(rs, 32);
            lsum += rs;

            bf16x8 pb0 = make_pfrag(s0[0], s0[1], s0[2],  s0[3],  s0[4],  s0[5],  s0[6],  s0[7]);
            bf16x8 pb1 = make_pfrag(s0[8], s0[9], s0[10], s0[11], s0[12], s0[13], s0[14], s0[15]);
            bf16x8 pb2 = make_pfrag(s1[0], s1[1], s1[2],  s1[3],  s1[4],  s1[5],  s1[6],  s1[7]);
            bf16x8 pb3 = make_pfrag(s1[8], s1[9], s1[10], s1[11], s1[12], s1[13], s1[14], s1[15]);

            __builtin_amdgcn_s_setprio(1);
#pragma unroll
            for (int db = 0; db < 4; ++db) {
                const int rd = (db << 5) + lo32;
                const char* vrow = (const char*)vbuf + rd * 128;
                const int sw = rd & 7;
                bf16x8 v0 = *(const bf16x8*)(vrow + (((0 + hl) ^ sw) << 4));
                o[db] = MFMA32(v0, pb0, o[db]);
                bf16x8 v1 = *(const bf16x8*)(vrow + (((2 + hl) ^ sw) << 4));
                o[db] = MFMA32(v1, pb1, o[db]);
                bf16x8 v2 = *(const bf16x8*)(vrow + (((4 + hl) ^ sw) << 4));
                o[db] = MFMA32(v2, pb2, o[db]);
                bf16x8 v3 = *(const bf16x8*)(vrow + (((6 + hl) ^ sw) << 4));
                o[db] = MFMA32(v3, pb3, o[db]);
            }
            __builtin_amdgcn_s_setprio(0);
        }
        cur ^= 1;
    }

    const float inv = 1.0f / lsum;
    const size_t rowoff = ((size_t)b * Tsz + qg) * (size_t)Csz + (size_t)h * 128;
#pragma unroll
    for (int db = 0; db < 4; ++db)
#pragma unroll
        for (int gg = 0; gg < 4; ++gg) {
            unsigned w0 = cvt_pk_bf16(o[db][4 * gg + 0] * inv, o[db][4 * gg + 1] * inv);
            unsigned w1 = cvt_pk_bf16(o[db][4 * gg + 2] * inv, o[db][4 * gg + 3] * inv);
            u32x2 w = {w0, w1};
            *(u32x2*)(Y + rowoff + (db << 5) + (gg << 3) + (hl << 2)) = w;
        }
}

extern "C" void kernel_launch(void* const* d_in, const int* in_sizes, int n_in,
                              void* d_out, int out_size, void* d_ws, size_t ws_size,
                              hipStream_t stream) {
    const float* x      = (const float*)d_in[0];
    const float* w_attn = (const float*)d_in[1];
    const float* w_proj = (const float*)d_in[2];
    float* out = (float*)d_out;

    char* ws = (char*)d_ws;
    bf16* Xb  = (bf16*)(ws);                 // 4096x2048           16 MB
    bf16* Wat = (bf16*)(ws + 16777216);      // 6144x2048 (W^T)     24 MB
    bf16* Wpt = (bf16*)(ws + 41943040);      // 2048x2048 (W^T)      8 MB
    bf16* Qr  = (bf16*)(ws + 50331648);      // [B,H,T,D] (scaled)  16 MB
    bf16* Kr  = (bf16*)(ws + 67108864);      // [B,H,T,D]           16 MB
    bf16* Vt  = (bf16*)(ws + 100663296);     // [B,H,D,T]           16 MB
    bf16* Yb  = (bf16*)(ws + 117440512);     // [B,T,C]             16 MB
    float2* cs = (float2*)(ws + 134217728);  // [T,64]               1 MB

    // single fused prep launch: cast + rope table + both weight transposes
    prep_all_kernel<<<8704, 256, 0, stream>>>(x, Xb, cs, w_attn, Wat, w_proj, Wpt);

    gemm384_qkv<<<512, 512, 0, stream>>>(Xb, Wat, Qr, Kr, Vt, cs, 2048);

    attn_kernel<<<dim3(512), 256, 0, stream>>>(Qr, Kr, Vt, Yb);

    gemm256_proj<<<256, 512, 0, stream>>>(Yb, Wpt, out, 2048);
}